// Round 6
// baseline (706.516 us; speedup 1.0000x reference)
//
#include <hip/hip_runtime.h>
#include <stdint.h>

#define BLK 256

static constexpr float F_EPS = 1e-7f;   // GENConv message eps
static constexpr float F_NEG = 0.01f;   // LeakyReLU slope
static constexpr int   TOPK  = 512;
static constexpr int   STATNB = 1024;   // stat_kernel grid (fixed, partial slots)
static constexpr int   BSH  = 9;        // bucket = dst >> BSH (512 nodes)
static constexpr int   NSUB = 8;        // sub-buckets (contention relief)
static constexpr int   BCAP = 1024;     // capacity per sub-bucket (mean ~765)

typedef unsigned long long u64;

__device__ __forceinline__ unsigned int ord_f32(float f) {
  unsigned int u = __float_as_uint(f);
  return (u & 0x80000000u) ? ~u : (u | 0x80000000u);
}

// ------- dense: out[n, j0:j0+JT] = in[n,:CIN] @ W[:, j0:j0+JT] + b -------
template<int CIN, int COUT, int JT>
__global__ __launch_bounds__(BLK) void lin_kernel(const float* __restrict__ in,
    const float* __restrict__ W, const float* __restrict__ b,
    float* __restrict__ out, int n) {
  __shared__ float sW[CIN * JT];
  __shared__ float sB[JT];
  const int j0 = blockIdx.y * JT;
  for (int i = threadIdx.x; i < CIN * JT; i += BLK) {
    int k = i / JT, jj = i - k * JT;
    sW[i] = W[k * COUT + j0 + jj];
  }
  for (int i = threadIdx.x; i < JT; i += BLK) sB[i] = b[j0 + i];
  __syncthreads();
  int node = blockIdx.x * BLK + threadIdx.x;
  if (node >= n) return;
  float acc[JT];
  #pragma unroll
  for (int jj = 0; jj < JT; ++jj) acc[jj] = sB[jj];
  const float* xrow = in + (size_t)node * CIN;
  if constexpr ((CIN & 3) == 0) {
    constexpr int KC = (CIN > 32) ? 32 : CIN;
    #pragma unroll
    for (int kc = 0; kc < CIN; kc += KC) {
      float x[KC];
      #pragma unroll
      for (int k4 = 0; k4 < KC / 4; ++k4) {
        float4 v = *reinterpret_cast<const float4*>(xrow + kc + k4 * 4);
        x[4*k4+0] = v.x; x[4*k4+1] = v.y; x[4*k4+2] = v.z; x[4*k4+3] = v.w;
      }
      #pragma unroll
      for (int k = 0; k < KC; ++k) {
        #pragma unroll
        for (int jj = 0; jj < JT; ++jj)
          acc[jj] += x[k] * sW[(kc + k) * JT + jj];
      }
    }
  } else {
    #pragma unroll
    for (int k = 0; k < CIN; ++k) {
      float xv = xrow[k];
      #pragma unroll
      for (int jj = 0; jj < JT; ++jj)
        acc[jj] += xv * sW[k * JT + jj];
    }
  }
  float* orow = out + (size_t)node * COUT + j0;
  #pragma unroll
  for (int jj = 0; jj < JT; jj += 4) {
    float4 r; r.x = acc[jj]; r.y = acc[jj+1]; r.z = acc[jj+2]; r.w = acc[jj+3];
    *reinterpret_cast<float4*>(orow + jj) = r;
  }
}

// ---- MLP second half: t=relu(h*scale+shift); out[, j-tile]=leaky(t@W+b) ----
template<int CIN, int COUT, int JT>
__global__ __launch_bounds__(BLK) void mlp2_kernel(const float* __restrict__ h,
    const float* __restrict__ scale, const float* __restrict__ shift,
    const float* __restrict__ W, const float* __restrict__ b,
    float* __restrict__ out, int n) {
  __shared__ float sW[CIN * JT];
  __shared__ float sB[JT];
  __shared__ float sSc[CIN];
  __shared__ float sSh[CIN];
  const int j0 = blockIdx.y * JT;
  for (int i = threadIdx.x; i < CIN * JT; i += BLK) {
    int k = i / JT, jj = i - k * JT;
    sW[i] = W[k * COUT + j0 + jj];
  }
  for (int i = threadIdx.x; i < JT; i += BLK) sB[i] = b[j0 + i];
  for (int i = threadIdx.x; i < CIN; i += BLK) { sSc[i] = scale[i]; sSh[i] = shift[i]; }
  __syncthreads();
  int node = blockIdx.x * BLK + threadIdx.x;
  if (node >= n) return;
  float acc[JT];
  #pragma unroll
  for (int jj = 0; jj < JT; ++jj) acc[jj] = sB[jj];
  const float* xrow = h + (size_t)node * CIN;
  constexpr int KC = (CIN > 32) ? 32 : CIN;
  #pragma unroll
  for (int kc = 0; kc < CIN; kc += KC) {
    float x[KC];
    #pragma unroll
    for (int k4 = 0; k4 < KC / 4; ++k4) {
      float4 v = *reinterpret_cast<const float4*>(xrow + kc + k4 * 4);
      x[4*k4+0] = fmaxf(v.x * sSc[kc+4*k4+0] + sSh[kc+4*k4+0], 0.f);
      x[4*k4+1] = fmaxf(v.y * sSc[kc+4*k4+1] + sSh[kc+4*k4+1], 0.f);
      x[4*k4+2] = fmaxf(v.z * sSc[kc+4*k4+2] + sSh[kc+4*k4+2], 0.f);
      x[4*k4+3] = fmaxf(v.w * sSc[kc+4*k4+3] + sSh[kc+4*k4+3], 0.f);
    }
    #pragma unroll
    for (int k = 0; k < KC; ++k) {
      #pragma unroll
      for (int jj = 0; jj < JT; ++jj)
        acc[jj] += x[k] * sW[(kc + k) * JT + jj];
    }
  }
  float* orow = out + (size_t)node * COUT + j0;
  #pragma unroll
  for (int jj = 0; jj < JT; jj += 4) {
    float a0 = acc[jj], a1 = acc[jj+1], a2 = acc[jj+2], a3 = acc[jj+3];
    a0 = a0 > 0.f ? a0 : F_NEG * a0;
    a1 = a1 > 0.f ? a1 : F_NEG * a1;
    a2 = a2 > 0.f ? a2 : F_NEG * a2;
    a3 = a3 > 0.f ? a3 : F_NEG * a3;
    float4 r; r.x = a0; r.y = a1; r.z = a2; r.w = a3;
    *reinterpret_cast<float4*>(orow + jj) = r;
  }
}

// ---------------- CSR build ----------------
__global__ __launch_bounds__(BLK) void deg_kernel(const int* __restrict__ dst,
    int* __restrict__ deg, int E) {
  int e = blockIdx.x * BLK + threadIdx.x;
  if (e < E) atomicAdd(&deg[dst[e]], 1);
}

__global__ __launch_bounds__(BLK) void blocksum_kernel(const int* __restrict__ deg,
    int* __restrict__ bsum, int n) {
  int i = blockIdx.x * BLK + threadIdx.x;
  int v = (i < n) ? deg[i] : 0;
  for (int off = 32; off; off >>= 1) v += __shfl_down(v, off);
  __shared__ int wsum[4];
  int lane = threadIdx.x & 63, wid = threadIdx.x >> 6;
  if (lane == 0) wsum[wid] = v;
  __syncthreads();
  if (threadIdx.x == 0) bsum[blockIdx.x] = wsum[0] + wsum[1] + wsum[2] + wsum[3];
}

__global__ __launch_bounds__(512) void scanb_kernel(int* __restrict__ bsum, int nb) {
  __shared__ int s[512];
  int t = threadIdx.x;
  int orig = (t < nb) ? bsum[t] : 0;
  s[t] = orig;
  __syncthreads();
  for (int off = 1; off < 512; off <<= 1) {
    int add = (t >= off) ? s[t - off] : 0;
    __syncthreads();
    s[t] += add;
    __syncthreads();
  }
  if (t < nb) bsum[t] = s[t] - orig;   // exclusive
}

__global__ __launch_bounds__(BLK) void rowstart_kernel(const int* __restrict__ deg,
    const int* __restrict__ bsum, int* __restrict__ rowstart,
    int* __restrict__ cursor, int n) {
  __shared__ int s[BLK];
  int t = threadIdx.x, i = blockIdx.x * BLK + t;
  int orig = (i < n) ? deg[i] : 0;
  s[t] = orig;
  __syncthreads();
  for (int off = 1; off < BLK; off <<= 1) {
    int add = (t >= off) ? s[t - off] : 0;
    __syncthreads();
    s[t] += add;
    __syncthreads();
  }
  if (i < n) { int st = bsum[blockIdx.x] + s[t] - orig; rowstart[i] = st; cursor[i] = st; }
}

// ---- pass A: append (src,dst) into sub-buckets keyed by dst>>BSH ----
// overflow (slot>=BCAP) falls back to direct cursor placement (rare/never)
__global__ __launch_bounds__(BLK) void bucket_kernel(const int* __restrict__ src,
    const int* __restrict__ dst, int* __restrict__ bcnt, int2* __restrict__ pairbuf,
    int* __restrict__ cursor, int* __restrict__ eidx, int E) {
  int e = blockIdx.x * BLK + threadIdx.x;
  if (e >= E) return;
  int d = dst[e], s = src[e];
  int bk = ((d >> BSH) << 3) + (blockIdx.x & (NSUB - 1));
  int slot = atomicAdd(&bcnt[bk], 1);
  if (slot < BCAP) {
    pairbuf[(size_t)bk * BCAP + slot] = make_int2(s, d);
  } else {
    int p = atomicAdd(&cursor[d], 1);
    eidx[p] = s;
  }
}

// ---- pass B: one block per bucket, place edges via (cache-local) cursors ----
__global__ __launch_bounds__(BLK) void place_kernel(const int* __restrict__ bcnt,
    const int2* __restrict__ pairbuf, int* __restrict__ cursor,
    int* __restrict__ eidx, int nbuk) {
  int b = blockIdx.x;
  if (b >= nbuk) return;
  for (int s = 0; s < NSUB; ++s) {
    int bk = b * NSUB + s;
    int cnt = bcnt[bk];
    cnt = cnt < BCAP ? cnt : BCAP;
    const int2* pb = pairbuf + (size_t)bk * BCAP;
    for (int i = threadIdx.x; i < cnt; i += BLK) {
      int2 pr = pb[i];
      int p = atomicAdd(&cursor[pr.y], 1);
      eidx[p] = pr.x;
    }
  }
}

// ---- fused gather-aggregate + residual: out = num/(den+1e-16) + x[d] ----
template<int C>
__global__ __launch_bounds__(BLK) void agg_kernel(const int* __restrict__ rowstart,
    const int* __restrict__ deg, const int* __restrict__ eidx,
    const float* __restrict__ x, float* __restrict__ out, int n) {
  int gid = blockIdx.x * BLK + threadIdx.x;
  int node = gid / C;
  int c = gid & (C - 1);
  if (node >= n) return;
  int s0 = rowstart[node];
  int d = deg[node];
  float den = 0.f, num = 0.f;
  int j = 0;
  for (; j + 3 < d; j += 4) {
    int sA = eidx[s0 + j], sB = eidx[s0 + j + 1];
    int sC = eidx[s0 + j + 2], sD = eidx[s0 + j + 3];
    float xa = x[(size_t)sA * C + c];
    float xb = x[(size_t)sB * C + c];
    float xc = x[(size_t)sC * C + c];
    float xd = x[(size_t)sD * C + c];
    float ma = fmaxf(xa, 0.f) + F_EPS;
    float mb = fmaxf(xb, 0.f) + F_EPS;
    float mc = fmaxf(xc, 0.f) + F_EPS;
    float md = fmaxf(xd, 0.f) + F_EPS;
    float aa = __expf(ma), ab = __expf(mb), ac = __expf(mc), ad = __expf(md);
    den += (aa + ab) + (ac + ad);
    num += (ma * aa + mb * ab) + (mc * ac + md * ad);
  }
  for (; j < d; ++j) {
    int sA = eidx[s0 + j];
    float xa = x[(size_t)sA * C + c];
    float ma = fmaxf(xa, 0.f) + F_EPS;
    float aa = __expf(ma);
    den += aa;
    num += ma * aa;
  }
  float xd = x[(size_t)node * C + c];
  out[(size_t)node * C + c] = num / (den + 1e-16f) + xd;
}

// ---- BN stats pass 1: per-block f64 partial column sums (NO atomics) ----
template<int COUT>
__global__ __launch_bounds__(BLK) void stat_kernel(const float* __restrict__ h,
    double* __restrict__ partial, int n) {
  constexpr int G = COUT / 4;
  constexpr int REPS = BLK / G;
  double s0 = 0, s1 = 0, s2 = 0, s3 = 0, q0 = 0, q1 = 0, q2 = 0, q3 = 0;
  int total4 = n * G;
  for (int i = blockIdx.x * BLK + threadIdx.x; i < total4; i += gridDim.x * BLK) {
    float4 v = reinterpret_cast<const float4*>(h)[i];
    double dx = v.x, dy = v.y, dz = v.z, dw = v.w;
    s0 += dx; q0 += dx * dx;
    s1 += dy; q1 += dy * dy;
    s2 += dz; q2 += dz * dz;
    s3 += dw; q3 += dw * dw;
  }
  __shared__ double sL[BLK * 8];
  double* my = sL + threadIdx.x * 8;
  my[0] = s0; my[1] = s1; my[2] = s2; my[3] = s3;
  my[4] = q0; my[5] = q1; my[6] = q2; my[7] = q3;
  __syncthreads();
  int g = threadIdx.x;
  if (g < G) {
    for (int r = 1; r < REPS; ++r) {
      double* o = sL + (g + r * G) * 8;
      s0 += o[0]; s1 += o[1]; s2 += o[2]; s3 += o[3];
      q0 += o[4]; q1 += o[5]; q2 += o[6]; q3 += o[7];
    }
    double* prow = partial + (size_t)blockIdx.x * (2 * COUT);
    prow[4*g+0] = s0; prow[4*g+1] = s1; prow[4*g+2] = s2; prow[4*g+3] = s3;
    prow[COUT+4*g+0] = q0; prow[COUT+4*g+1] = q1;
    prow[COUT+4*g+2] = q2; prow[COUT+4*g+3] = q3;
  }
}

// ---- BN stats pass 2: one block per channel reduces STATNB partials ----
template<int COUT>
__global__ __launch_bounds__(256) void bn_fin2(const double* __restrict__ partial,
    const float* __restrict__ g, const float* __restrict__ be,
    float* __restrict__ sc, float* __restrict__ sh, int n) {
  int j = blockIdx.x;
  int t = threadIdx.x;
  double s = 0, q = 0;
  for (int b = t; b < STATNB; b += 256) {
    const double* prow = partial + (size_t)b * (2 * COUT);
    s += prow[j];
    q += prow[COUT + j];
  }
  for (int off = 32; off; off >>= 1) { s += __shfl_down(s, off); q += __shfl_down(q, off); }
  __shared__ double sw[4][2];
  int lane = t & 63, wid = t >> 6;
  if (lane == 0) { sw[wid][0] = s; sw[wid][1] = q; }
  __syncthreads();
  if (t == 0) {
    s = sw[0][0] + sw[1][0] + sw[2][0] + sw[3][0];
    q = sw[0][1] + sw[1][1] + sw[2][1] + sw[3][1];
    double inv_n = 1.0 / (double)n;
    double mu = s * inv_n;
    double var = q * inv_n - mu * mu;
    double scd = (double)g[j] / sqrt(var + 1e-5);
    sc[j] = (float)scd;
    sh[j] = (float)((double)be[j] - mu * scd);
  }
}

// ---- score + key + round-0 histogram (byte 7) ----
__global__ __launch_bounds__(BLK) void score_kernel(const float* __restrict__ x,
    const float* __restrict__ w, float* __restrict__ scores,
    u64* __restrict__ keys, int* __restrict__ ghist, int n) {
  __shared__ float sw[64];
  __shared__ float snorm;
  __shared__ int hl[256];
  if (threadIdx.x < 64) sw[threadIdx.x] = w[threadIdx.x];
  hl[threadIdx.x] = 0;
  __syncthreads();
  if (threadIdx.x < 64) {
    float v = sw[threadIdx.x];
    float sq = v * v;
    for (int off = 32; off; off >>= 1) sq += __shfl_down(sq, off);
    if (threadIdx.x == 0) snorm = 1.f / sqrtf(sq);
  }
  __syncthreads();
  int node = blockIdx.x * BLK + threadIdx.x;
  if (node < n) {
    const float4* row = reinterpret_cast<const float4*>(x + (size_t)node * 64);
    float acc = 0.f;
    #pragma unroll
    for (int k4 = 0; k4 < 16; ++k4) {
      float4 v = row[k4];
      const float4 wv = *reinterpret_cast<const float4*>(&sw[4 * k4]);
      acc += v.x * wv.x + v.y * wv.y + v.z * wv.z + v.w * wv.w;
    }
    float s = tanhf(acc * snorm);
    scores[node] = s;
    u64 key = ((u64)ord_f32(s) << 32) | (unsigned int)(~node);
    keys[node] = key;
    atomicAdd(&hl[(int)(key >> 56)], 1);
  }
  __syncthreads();
  int v = hl[threadIdx.x];
  if (v) atomicAdd(&ghist[threadIdx.x], v);
}

// istate: [0]=k remaining [1]=digit [2]=sel count [4]=out count
__global__ void pick0_kernel(int* __restrict__ istate, const int* __restrict__ hist) {
  if (threadIdx.x == 0) {
    int k = TOPK, run = 0;
    for (int d = 255; d >= 0; --d) {
      int c = hist[d];
      if (run + c >= k) { istate[1] = d; istate[0] = k - run; break; }
      run += c;
    }
    istate[2] = 0; istate[4] = 0;
  }
}

__global__ __launch_bounds__(BLK) void compact0_kernel(const u64* __restrict__ in,
    u64* __restrict__ outb, u64* __restrict__ sel, int* __restrict__ istate, int n) {
  int i = blockIdx.x * BLK + threadIdx.x;
  if (i >= n) return;
  u64 kkey = in[i];
  int b = (int)(kkey >> 56);
  int digit = istate[1];
  if (b > digit) {
    sel[atomicAdd(&istate[2], 1)] = kkey;
  } else if (b == digit) {
    outb[atomicAdd(&istate[4], 1)] = kkey;
  }
}

// ---- single block: radix rounds 1..7 + append + bitonic sort + gather ----
__global__ __launch_bounds__(1024) void topk_finish(u64* __restrict__ bufB,
    u64* __restrict__ bufA, u64* __restrict__ sel, const int* __restrict__ istate,
    const float* __restrict__ scores, const float* __restrict__ x,
    float* __restrict__ out) {
  __shared__ int hl[256];
  __shared__ int sh_digit, sh_k, sh_sel, sh_out, sh_cnt;
  __shared__ u64 sk[512];
  int t = threadIdx.x;
  if (t == 0) { sh_cnt = istate[4]; sh_k = istate[0]; sh_sel = istate[2]; }
  __syncthreads();
  u64* cur = bufB;
  u64* nxt = bufA;
  for (int shift = 48; shift >= 0; shift -= 8) {
    for (int i = t; i < 256; i += 1024) hl[i] = 0;
    __syncthreads();
    int cnt = sh_cnt;
    for (int i = t; i < cnt; i += 1024) atomicAdd(&hl[(int)((cur[i] >> shift) & 255ull)], 1);
    __syncthreads();
    if (t == 0) {
      int k = sh_k, run = 0;
      for (int d = 255; d >= 0; --d) {
        int c = hl[d];
        if (run + c >= k) { sh_digit = d; sh_k = k - run; break; }
        run += c;
      }
      sh_out = 0;
    }
    __syncthreads();
    int digit = sh_digit;
    for (int i = t; i < cnt; i += 1024) {
      u64 kk = cur[i];
      int b = (int)((kk >> shift) & 255ull);
      if (b > digit) sel[atomicAdd(&sh_sel, 1)] = kk;
      else if (b == digit) nxt[atomicAdd(&sh_out, 1)] = kk;
    }
    __syncthreads();
    if (t == 0) sh_cnt = sh_out;
    __syncthreads();
    u64* tmp = cur; cur = nxt; nxt = tmp;
  }
  int base = sh_sel, krem = sh_k;
  for (int i = t; i < krem; i += 1024) sel[base + i] = cur[i];
  __syncthreads();
  if (t < 512) sk[t] = sel[t];
  __syncthreads();
  for (int k = 2; k <= 512; k <<= 1) {
    for (int j = k >> 1; j > 0; j >>= 1) {
      if (t < 512) {
        int ixj = t ^ j;
        if (ixj > t) {
          bool dirDesc = ((t & k) == 0);
          u64 A = sk[t], B = sk[ixj];
          bool swp = dirDesc ? (A < B) : (A > B);
          if (swp) { sk[t] = B; sk[ixj] = A; }
        }
      }
      __syncthreads();
    }
  }
  for (int i = t; i < 512 * 16; i += 1024) {
    int r = i >> 4, c = i & 15;
    u64 kk = sk[r];
    int nidx = (int)(~(unsigned int)(kk & 0xffffffffull));
    float v = scores[nidx];
    float4 xv = reinterpret_cast<const float4*>(x)[(size_t)nidx * 16 + c];
    float4 r4; r4.x = xv.x * v; r4.y = xv.y * v; r4.z = xv.z * v; r4.w = xv.w * v;
    reinterpret_cast<float4*>(out)[(size_t)r * 16 + c] = r4;
  }
}

extern "C" void kernel_launch(void* const* d_in, const int* in_sizes, int n_in,
                              void* d_out, int out_size, void* d_ws, size_t ws_size,
                              hipStream_t stream) {
  const int N = in_sizes[0] / 3;
  const int E = in_sizes[1] / 2;
  const int NBUK = (N + (1 << BSH) - 1) >> BSH;

  const float* pos   = (const float*)d_in[0];
  const int*   ei    = (const int*)d_in[1];
  const int*   src   = ei;
  const int*   dst   = ei + E;
  const float* c1_lw = (const float*)d_in[2];
  const float* c1_lb = (const float*)d_in[3];
  const float* c1_w1 = (const float*)d_in[4];
  const float* c1_b1 = (const float*)d_in[5];
  const float* c1_g1 = (const float*)d_in[6];
  const float* c1_be1= (const float*)d_in[7];
  const float* c1_w2 = (const float*)d_in[8];
  const float* c1_b2 = (const float*)d_in[9];
  const float* c2_lw = (const float*)d_in[10];
  const float* c2_lb = (const float*)d_in[11];
  const float* c2_w1 = (const float*)d_in[12];
  const float* c2_b1 = (const float*)d_in[13];
  const float* c2_g1 = (const float*)d_in[14];
  const float* c2_be1= (const float*)d_in[15];
  const float* c2_w2 = (const float*)d_in[16];
  const float* c2_b2 = (const float*)d_in[17];
  const float* poolw = (const float*)d_in[18];

  // ---- workspace layout ----
  float* ws = (float*)d_ws;
  float* x1   = ws;                         // 16N
  float* h1   = ws + (size_t)16 * N;        // 32N
  float* o1   = ws + (size_t)48 * N;        // 16N
  float* res2 = ws;                         // 64N (after x1/h1/o1 dead)
  float* x2   = ws + (size_t)64 * N;        // 64N (res1 uses this region first)
  float* res1 = x2;                         // 16N (dead before lin<16,64> writes x2)
  float* h2   = ws + (size_t)128 * N;       // 128N
  float* o2   = ws + (size_t)256 * N;       // 64N
  float* scores = ws + (size_t)320 * N;     // N
  u64* candA = (u64*)(ws + (size_t)321 * N);            // N
  u64* candB = candA + N;                               // N
  u64* sel   = candB + N;                               // 512
  double* partial = (double*)(sel + TOPK);              // STATNB * 256 doubles (2 MB)
  int* ibase   = (int*)(partial + (size_t)STATNB * 256);
  int* istate  = ibase;            // 8
  int* hist    = ibase + 8;        // 256
  int* bsum    = ibase + 264;      // 512
  int* bcnt    = ibase + 776;      // NBUK*NSUB
  int* deg     = bcnt + NBUK * NSUB;   // N
  int* rowstart= deg + N;          // N
  int* cursor  = rowstart + N;     // N
  int* eidx    = cursor + N;       // E
  int2* pairbuf = (int2*)(((uintptr_t)(eidx + E) + 7) & ~(uintptr_t)7);  // NBUK*NSUB*BCAP
  float* fsc   = (float*)(pairbuf + (size_t)NBUK * NSUB * BCAP);
  float* sc1 = fsc;        float* sh1 = fsc + 32;
  float* sc2 = fsc + 64;   float* sh2 = fsc + 192;     // 320 floats total

  const int nbN = (N + BLK - 1) / BLK;
  const int nbE = (E + BLK - 1) / BLK;

  // replay-safe zeroing: istate..deg (hist, bcnt, deg are atomic targets)
  hipMemsetAsync(ibase, 0, (size_t)(776 + NBUK * NSUB + N) * sizeof(int), stream);

  // ---- CSR build (shared by both convs) ----
  deg_kernel<<<nbE, BLK, 0, stream>>>(dst, deg, E);
  blocksum_kernel<<<nbN, BLK, 0, stream>>>(deg, bsum, N);
  scanb_kernel<<<1, 512, 0, stream>>>(bsum, nbN);
  rowstart_kernel<<<nbN, BLK, 0, stream>>>(deg, bsum, rowstart, cursor, N);
  bucket_kernel<<<nbE, BLK, 0, stream>>>(src, dst, bcnt, pairbuf, cursor, eidx, E);
  place_kernel<<<NBUK, BLK, 0, stream>>>(bcnt, pairbuf, cursor, eidx, NBUK);

  // ---- conv1 ----
  lin_kernel<3, 16, 16><<<dim3(nbN, 1), BLK, 0, stream>>>(pos, c1_lw, c1_lb, x1, N);
  agg_kernel<16><<<(N * 16 + BLK - 1) / BLK, BLK, 0, stream>>>(rowstart, deg, eidx, x1, res1, N);
  lin_kernel<16, 32, 32><<<dim3(nbN, 1), BLK, 0, stream>>>(res1, c1_w1, c1_b1, h1, N);
  stat_kernel<32><<<STATNB, BLK, 0, stream>>>(h1, partial, N);
  bn_fin2<32><<<32, 256, 0, stream>>>(partial, c1_g1, c1_be1, sc1, sh1, N);
  mlp2_kernel<32, 16, 16><<<dim3(nbN, 1), BLK, 0, stream>>>(h1, sc1, sh1, c1_w2, c1_b2, o1, N);

  // ---- conv2 ----
  lin_kernel<16, 64, 32><<<dim3(nbN, 2), BLK, 0, stream>>>(o1, c2_lw, c2_lb, x2, N);
  agg_kernel<64><<<(N * 64 + BLK - 1) / BLK, BLK, 0, stream>>>(rowstart, deg, eidx, x2, res2, N);
  lin_kernel<64, 128, 32><<<dim3(nbN, 4), BLK, 0, stream>>>(res2, c2_w1, c2_b1, h2, N);
  stat_kernel<128><<<STATNB, BLK, 0, stream>>>(h2, partial, N);
  bn_fin2<128><<<128, 256, 0, stream>>>(partial, c2_g1, c2_be1, sc2, sh2, N);
  mlp2_kernel<128, 64, 32><<<dim3(nbN, 2), BLK, 0, stream>>>(h2, sc2, sh2, c2_w2, c2_b2, o2, N);

  // ---- scores + exact top-K ----
  score_kernel<<<nbN, BLK, 0, stream>>>(o2, poolw, scores, candA, hist, N);
  pick0_kernel<<<1, 64, 0, stream>>>(istate, hist);
  compact0_kernel<<<nbN, BLK, 0, stream>>>(candA, candB, sel, istate, N);
  topk_finish<<<1, 1024, 0, stream>>>(candB, candA, sel, istate, scores, o2, (float*)d_out);

  (void)n_in; (void)out_size; (void)ws_size;
}

// Round 7
// 547.010 us; speedup vs baseline: 1.2916x; 1.2916x over previous
//
#include <hip/hip_runtime.h>
#include <stdint.h>

#define BLK 256

static constexpr float F_EPS = 1e-7f;   // GENConv message eps
static constexpr float F_NEG = 0.01f;   // LeakyReLU slope
static constexpr int   TOPK  = 512;
static constexpr int   STATNB = 1024;   // stat_kernel grid (fixed, partial slots)

typedef unsigned long long u64;

__device__ __forceinline__ unsigned int ord_f32(float f) {
  unsigned int u = __float_as_uint(f);
  return (u & 0x80000000u) ? ~u : (u | 0x80000000u);
}

// ------- dense: out[n, j0:j0+JT] = in[n,:CIN] @ W[:, j0:j0+JT] + b -------
template<int CIN, int COUT, int JT>
__global__ __launch_bounds__(BLK) void lin_kernel(const float* __restrict__ in,
    const float* __restrict__ W, const float* __restrict__ b,
    float* __restrict__ out, int n) {
  __shared__ float sW[CIN * JT];
  __shared__ float sB[JT];
  const int j0 = blockIdx.y * JT;
  for (int i = threadIdx.x; i < CIN * JT; i += BLK) {
    int k = i / JT, jj = i - k * JT;
    sW[i] = W[k * COUT + j0 + jj];
  }
  for (int i = threadIdx.x; i < JT; i += BLK) sB[i] = b[j0 + i];
  __syncthreads();
  int node = blockIdx.x * BLK + threadIdx.x;
  if (node >= n) return;
  float acc[JT];
  #pragma unroll
  for (int jj = 0; jj < JT; ++jj) acc[jj] = sB[jj];
  const float* xrow = in + (size_t)node * CIN;
  if constexpr ((CIN & 3) == 0) {
    constexpr int KC = (CIN > 32) ? 32 : CIN;
    #pragma unroll
    for (int kc = 0; kc < CIN; kc += KC) {
      float x[KC];
      #pragma unroll
      for (int k4 = 0; k4 < KC / 4; ++k4) {
        float4 v = *reinterpret_cast<const float4*>(xrow + kc + k4 * 4);
        x[4*k4+0] = v.x; x[4*k4+1] = v.y; x[4*k4+2] = v.z; x[4*k4+3] = v.w;
      }
      #pragma unroll
      for (int k = 0; k < KC; ++k) {
        #pragma unroll
        for (int jj = 0; jj < JT; ++jj)
          acc[jj] += x[k] * sW[(kc + k) * JT + jj];
      }
    }
  } else {
    #pragma unroll
    for (int k = 0; k < CIN; ++k) {
      float xv = xrow[k];
      #pragma unroll
      for (int jj = 0; jj < JT; ++jj)
        acc[jj] += xv * sW[k * JT + jj];
    }
  }
  float* orow = out + (size_t)node * COUT + j0;
  #pragma unroll
  for (int jj = 0; jj < JT; jj += 4) {
    float4 r; r.x = acc[jj]; r.y = acc[jj+1]; r.z = acc[jj+2]; r.w = acc[jj+3];
    *reinterpret_cast<float4*>(orow + jj) = r;
  }
}

// ---- MLP second half: t=relu(h*scale+shift); out[, j-tile]=leaky(t@W+b) ----
template<int CIN, int COUT, int JT>
__global__ __launch_bounds__(BLK) void mlp2_kernel(const float* __restrict__ h,
    const float* __restrict__ scale, const float* __restrict__ shift,
    const float* __restrict__ W, const float* __restrict__ b,
    float* __restrict__ out, int n) {
  __shared__ float sW[CIN * JT];
  __shared__ float sB[JT];
  __shared__ float sSc[CIN];
  __shared__ float sSh[CIN];
  const int j0 = blockIdx.y * JT;
  for (int i = threadIdx.x; i < CIN * JT; i += BLK) {
    int k = i / JT, jj = i - k * JT;
    sW[i] = W[k * COUT + j0 + jj];
  }
  for (int i = threadIdx.x; i < JT; i += BLK) sB[i] = b[j0 + i];
  for (int i = threadIdx.x; i < CIN; i += BLK) { sSc[i] = scale[i]; sSh[i] = shift[i]; }
  __syncthreads();
  int node = blockIdx.x * BLK + threadIdx.x;
  if (node >= n) return;
  float acc[JT];
  #pragma unroll
  for (int jj = 0; jj < JT; ++jj) acc[jj] = sB[jj];
  const float* xrow = h + (size_t)node * CIN;
  constexpr int KC = (CIN > 32) ? 32 : CIN;
  #pragma unroll
  for (int kc = 0; kc < CIN; kc += KC) {
    float x[KC];
    #pragma unroll
    for (int k4 = 0; k4 < KC / 4; ++k4) {
      float4 v = *reinterpret_cast<const float4*>(xrow + kc + k4 * 4);
      x[4*k4+0] = fmaxf(v.x * sSc[kc+4*k4+0] + sSh[kc+4*k4+0], 0.f);
      x[4*k4+1] = fmaxf(v.y * sSc[kc+4*k4+1] + sSh[kc+4*k4+1], 0.f);
      x[4*k4+2] = fmaxf(v.z * sSc[kc+4*k4+2] + sSh[kc+4*k4+2], 0.f);
      x[4*k4+3] = fmaxf(v.w * sSc[kc+4*k4+3] + sSh[kc+4*k4+3], 0.f);
    }
    #pragma unroll
    for (int k = 0; k < KC; ++k) {
      #pragma unroll
      for (int jj = 0; jj < JT; ++jj)
        acc[jj] += x[k] * sW[(kc + k) * JT + jj];
    }
  }
  float* orow = out + (size_t)node * COUT + j0;
  #pragma unroll
  for (int jj = 0; jj < JT; jj += 4) {
    float a0 = acc[jj], a1 = acc[jj+1], a2 = acc[jj+2], a3 = acc[jj+3];
    a0 = a0 > 0.f ? a0 : F_NEG * a0;
    a1 = a1 > 0.f ? a1 : F_NEG * a1;
    a2 = a2 > 0.f ? a2 : F_NEG * a2;
    a3 = a3 > 0.f ? a3 : F_NEG * a3;
    float4 r; r.x = a0; r.y = a1; r.z = a2; r.w = a3;
    *reinterpret_cast<float4*>(orow + jj) = r;
  }
}

// ---------------- CSR build ----------------
__global__ __launch_bounds__(BLK) void deg_kernel(const int* __restrict__ dst,
    int* __restrict__ deg, int E) {
  int e = blockIdx.x * BLK + threadIdx.x;
  if (e < E) atomicAdd(&deg[dst[e]], 1);
}

__global__ __launch_bounds__(BLK) void blocksum_kernel(const int* __restrict__ deg,
    int* __restrict__ bsum, int n) {
  int i = blockIdx.x * BLK + threadIdx.x;
  int v = (i < n) ? deg[i] : 0;
  for (int off = 32; off; off >>= 1) v += __shfl_down(v, off);
  __shared__ int wsum[4];
  int lane = threadIdx.x & 63, wid = threadIdx.x >> 6;
  if (lane == 0) wsum[wid] = v;
  __syncthreads();
  if (threadIdx.x == 0) bsum[blockIdx.x] = wsum[0] + wsum[1] + wsum[2] + wsum[3];
}

__global__ __launch_bounds__(512) void scanb_kernel(int* __restrict__ bsum, int nb) {
  __shared__ int s[512];
  int t = threadIdx.x;
  int orig = (t < nb) ? bsum[t] : 0;
  s[t] = orig;
  __syncthreads();
  for (int off = 1; off < 512; off <<= 1) {
    int add = (t >= off) ? s[t - off] : 0;
    __syncthreads();
    s[t] += add;
    __syncthreads();
  }
  if (t < nb) bsum[t] = s[t] - orig;   // exclusive
}

__global__ __launch_bounds__(BLK) void rowstart_kernel(const int* __restrict__ deg,
    const int* __restrict__ bsum, int* __restrict__ rowstart,
    int* __restrict__ cursor, int n) {
  __shared__ int s[BLK];
  int t = threadIdx.x, i = blockIdx.x * BLK + t;
  int orig = (i < n) ? deg[i] : 0;
  s[t] = orig;
  __syncthreads();
  for (int off = 1; off < BLK; off <<= 1) {
    int add = (t >= off) ? s[t - off] : 0;
    __syncthreads();
    s[t] += add;
    __syncthreads();
  }
  if (i < n) { int st = bsum[blockIdx.x] + s[t] - orig; rowstart[i] = st; cursor[i] = st; }
}

__global__ __launch_bounds__(BLK) void scatter_kernel(const int* __restrict__ src,
    const int* __restrict__ dst, int* __restrict__ cursor, int* __restrict__ eidx, int E) {
  int e = blockIdx.x * BLK + threadIdx.x;
  if (e >= E) return;
  int p = atomicAdd(&cursor[dst[e]], 1);
  eidx[p] = src[e];
}

// ---- fused gather-aggregate + residual: out = num/(den+1e-16) + x[d] ----
template<int C>
__global__ __launch_bounds__(BLK) void agg_kernel(const int* __restrict__ rowstart,
    const int* __restrict__ deg, const int* __restrict__ eidx,
    const float* __restrict__ x, float* __restrict__ out, int n) {
  int gid = blockIdx.x * BLK + threadIdx.x;
  int node = gid / C;
  int c = gid & (C - 1);
  if (node >= n) return;
  int s0 = rowstart[node];
  int d = deg[node];
  float den = 0.f, num = 0.f;
  int j = 0;
  for (; j + 3 < d; j += 4) {
    int sA = eidx[s0 + j], sB = eidx[s0 + j + 1];
    int sC = eidx[s0 + j + 2], sD = eidx[s0 + j + 3];
    float xa = x[(size_t)sA * C + c];
    float xb = x[(size_t)sB * C + c];
    float xc = x[(size_t)sC * C + c];
    float xd = x[(size_t)sD * C + c];
    float ma = fmaxf(xa, 0.f) + F_EPS;
    float mb = fmaxf(xb, 0.f) + F_EPS;
    float mc = fmaxf(xc, 0.f) + F_EPS;
    float md = fmaxf(xd, 0.f) + F_EPS;
    float aa = __expf(ma), ab = __expf(mb), ac = __expf(mc), ad = __expf(md);
    den += (aa + ab) + (ac + ad);
    num += (ma * aa + mb * ab) + (mc * ac + md * ad);
  }
  for (; j < d; ++j) {
    int sA = eidx[s0 + j];
    float xa = x[(size_t)sA * C + c];
    float ma = fmaxf(xa, 0.f) + F_EPS;
    float aa = __expf(ma);
    den += aa;
    num += ma * aa;
  }
  float xd = x[(size_t)node * C + c];
  out[(size_t)node * C + c] = num / (den + 1e-16f) + xd;
}

// ---- BN stats pass 1: per-block f64 partial column sums (NO atomics) ----
template<int COUT>
__global__ __launch_bounds__(BLK) void stat_kernel(const float* __restrict__ h,
    double* __restrict__ partial, int n) {
  constexpr int G = COUT / 4;
  constexpr int REPS = BLK / G;
  double s0 = 0, s1 = 0, s2 = 0, s3 = 0, q0 = 0, q1 = 0, q2 = 0, q3 = 0;
  int total4 = n * G;
  for (int i = blockIdx.x * BLK + threadIdx.x; i < total4; i += gridDim.x * BLK) {
    float4 v = reinterpret_cast<const float4*>(h)[i];
    double dx = v.x, dy = v.y, dz = v.z, dw = v.w;
    s0 += dx; q0 += dx * dx;
    s1 += dy; q1 += dy * dy;
    s2 += dz; q2 += dz * dz;
    s3 += dw; q3 += dw * dw;
  }
  __shared__ double sL[BLK * 8];
  double* my = sL + threadIdx.x * 8;
  my[0] = s0; my[1] = s1; my[2] = s2; my[3] = s3;
  my[4] = q0; my[5] = q1; my[6] = q2; my[7] = q3;
  __syncthreads();
  int g = threadIdx.x;
  if (g < G) {
    for (int r = 1; r < REPS; ++r) {
      double* o = sL + (g + r * G) * 8;
      s0 += o[0]; s1 += o[1]; s2 += o[2]; s3 += o[3];
      q0 += o[4]; q1 += o[5]; q2 += o[6]; q3 += o[7];
    }
    double* prow = partial + (size_t)blockIdx.x * (2 * COUT);
    prow[4*g+0] = s0; prow[4*g+1] = s1; prow[4*g+2] = s2; prow[4*g+3] = s3;
    prow[COUT+4*g+0] = q0; prow[COUT+4*g+1] = q1;
    prow[COUT+4*g+2] = q2; prow[COUT+4*g+3] = q3;
  }
}

// ---- BN stats pass 2: one block per channel reduces STATNB partials ----
template<int COUT>
__global__ __launch_bounds__(256) void bn_fin2(const double* __restrict__ partial,
    const float* __restrict__ g, const float* __restrict__ be,
    float* __restrict__ sc, float* __restrict__ sh, int n) {
  int j = blockIdx.x;
  int t = threadIdx.x;
  double s = 0, q = 0;
  for (int b = t; b < STATNB; b += 256) {
    const double* prow = partial + (size_t)b * (2 * COUT);
    s += prow[j];
    q += prow[COUT + j];
  }
  for (int off = 32; off; off >>= 1) { s += __shfl_down(s, off); q += __shfl_down(q, off); }
  __shared__ double sw[4][2];
  int lane = t & 63, wid = t >> 6;
  if (lane == 0) { sw[wid][0] = s; sw[wid][1] = q; }
  __syncthreads();
  if (t == 0) {
    s = sw[0][0] + sw[1][0] + sw[2][0] + sw[3][0];
    q = sw[0][1] + sw[1][1] + sw[2][1] + sw[3][1];
    double inv_n = 1.0 / (double)n;
    double mu = s * inv_n;
    double var = q * inv_n - mu * mu;
    double scd = (double)g[j] / sqrt(var + 1e-5);
    sc[j] = (float)scd;
    sh[j] = (float)((double)be[j] - mu * scd);
  }
}

// ---- score + key + round-0 histogram (byte 7) ----
__global__ __launch_bounds__(BLK) void score_kernel(const float* __restrict__ x,
    const float* __restrict__ w, float* __restrict__ scores,
    u64* __restrict__ keys, int* __restrict__ ghist, int n) {
  __shared__ float sw[64];
  __shared__ float snorm;
  __shared__ int hl[256];
  if (threadIdx.x < 64) sw[threadIdx.x] = w[threadIdx.x];
  hl[threadIdx.x] = 0;
  __syncthreads();
  if (threadIdx.x < 64) {
    float v = sw[threadIdx.x];
    float sq = v * v;
    for (int off = 32; off; off >>= 1) sq += __shfl_down(sq, off);
    if (threadIdx.x == 0) snorm = 1.f / sqrtf(sq);
  }
  __syncthreads();
  int node = blockIdx.x * BLK + threadIdx.x;
  if (node < n) {
    const float4* row = reinterpret_cast<const float4*>(x + (size_t)node * 64);
    float acc = 0.f;
    #pragma unroll
    for (int k4 = 0; k4 < 16; ++k4) {
      float4 v = row[k4];
      const float4 wv = *reinterpret_cast<const float4*>(&sw[4 * k4]);
      acc += v.x * wv.x + v.y * wv.y + v.z * wv.z + v.w * wv.w;
    }
    float s = tanhf(acc * snorm);
    scores[node] = s;
    u64 key = ((u64)ord_f32(s) << 32) | (unsigned int)(~node);
    keys[node] = key;
    atomicAdd(&hl[(int)(key >> 56)], 1);
  }
  __syncthreads();
  int v = hl[threadIdx.x];
  if (v) atomicAdd(&ghist[threadIdx.x], v);
}

// istate: [0]=k remaining [1]=digit [2]=sel count [4]=out count
__global__ void pick0_kernel(int* __restrict__ istate, const int* __restrict__ hist) {
  if (threadIdx.x == 0) {
    int k = TOPK, run = 0;
    for (int d = 255; d >= 0; --d) {
      int c = hist[d];
      if (run + c >= k) { istate[1] = d; istate[0] = k - run; break; }
      run += c;
    }
    istate[2] = 0; istate[4] = 0;
  }
}

__global__ __launch_bounds__(BLK) void compact0_kernel(const u64* __restrict__ in,
    u64* __restrict__ outb, u64* __restrict__ sel, int* __restrict__ istate, int n) {
  int i = blockIdx.x * BLK + threadIdx.x;
  if (i >= n) return;
  u64 kkey = in[i];
  int b = (int)(kkey >> 56);
  int digit = istate[1];
  if (b > digit) {
    sel[atomicAdd(&istate[2], 1)] = kkey;
  } else if (b == digit) {
    outb[atomicAdd(&istate[4], 1)] = kkey;
  }
}

// ---- single block: radix rounds 1..7 + append + bitonic sort + gather ----
__global__ __launch_bounds__(1024) void topk_finish(u64* __restrict__ bufB,
    u64* __restrict__ bufA, u64* __restrict__ sel, const int* __restrict__ istate,
    const float* __restrict__ scores, const float* __restrict__ x,
    float* __restrict__ out) {
  __shared__ int hl[256];
  __shared__ int sh_digit, sh_k, sh_sel, sh_out, sh_cnt;
  __shared__ u64 sk[512];
  int t = threadIdx.x;
  if (t == 0) { sh_cnt = istate[4]; sh_k = istate[0]; sh_sel = istate[2]; }
  __syncthreads();
  u64* cur = bufB;
  u64* nxt = bufA;
  for (int shift = 48; shift >= 0; shift -= 8) {
    for (int i = t; i < 256; i += 1024) hl[i] = 0;
    __syncthreads();
    int cnt = sh_cnt;
    for (int i = t; i < cnt; i += 1024) atomicAdd(&hl[(int)((cur[i] >> shift) & 255ull)], 1);
    __syncthreads();
    if (t == 0) {
      int k = sh_k, run = 0;
      for (int d = 255; d >= 0; --d) {
        int c = hl[d];
        if (run + c >= k) { sh_digit = d; sh_k = k - run; break; }
        run += c;
      }
      sh_out = 0;
    }
    __syncthreads();
    int digit = sh_digit;
    for (int i = t; i < cnt; i += 1024) {
      u64 kk = cur[i];
      int b = (int)((kk >> shift) & 255ull);
      if (b > digit) sel[atomicAdd(&sh_sel, 1)] = kk;
      else if (b == digit) nxt[atomicAdd(&sh_out, 1)] = kk;
    }
    __syncthreads();
    if (t == 0) sh_cnt = sh_out;
    __syncthreads();
    u64* tmp = cur; cur = nxt; nxt = tmp;
  }
  int base = sh_sel, krem = sh_k;
  for (int i = t; i < krem; i += 1024) sel[base + i] = cur[i];
  __syncthreads();
  if (t < 512) sk[t] = sel[t];
  __syncthreads();
  for (int k = 2; k <= 512; k <<= 1) {
    for (int j = k >> 1; j > 0; j >>= 1) {
      if (t < 512) {
        int ixj = t ^ j;
        if (ixj > t) {
          bool dirDesc = ((t & k) == 0);
          u64 A = sk[t], B = sk[ixj];
          bool swp = dirDesc ? (A < B) : (A > B);
          if (swp) { sk[t] = B; sk[ixj] = A; }
        }
      }
      __syncthreads();
    }
  }
  for (int i = t; i < 512 * 16; i += 1024) {
    int r = i >> 4, c = i & 15;
    u64 kk = sk[r];
    int nidx = (int)(~(unsigned int)(kk & 0xffffffffull));
    float v = scores[nidx];
    float4 xv = reinterpret_cast<const float4*>(x)[(size_t)nidx * 16 + c];
    float4 r4; r4.x = xv.x * v; r4.y = xv.y * v; r4.z = xv.z * v; r4.w = xv.w * v;
    reinterpret_cast<float4*>(out)[(size_t)r * 16 + c] = r4;
  }
}

extern "C" void kernel_launch(void* const* d_in, const int* in_sizes, int n_in,
                              void* d_out, int out_size, void* d_ws, size_t ws_size,
                              hipStream_t stream) {
  const int N = in_sizes[0] / 3;
  const int E = in_sizes[1] / 2;

  const float* pos   = (const float*)d_in[0];
  const int*   ei    = (const int*)d_in[1];
  const int*   src   = ei;
  const int*   dst   = ei + E;
  const float* c1_lw = (const float*)d_in[2];
  const float* c1_lb = (const float*)d_in[3];
  const float* c1_w1 = (const float*)d_in[4];
  const float* c1_b1 = (const float*)d_in[5];
  const float* c1_g1 = (const float*)d_in[6];
  const float* c1_be1= (const float*)d_in[7];
  const float* c1_w2 = (const float*)d_in[8];
  const float* c1_b2 = (const float*)d_in[9];
  const float* c2_lw = (const float*)d_in[10];
  const float* c2_lb = (const float*)d_in[11];
  const float* c2_w1 = (const float*)d_in[12];
  const float* c2_b1 = (const float*)d_in[13];
  const float* c2_g1 = (const float*)d_in[14];
  const float* c2_be1= (const float*)d_in[15];
  const float* c2_w2 = (const float*)d_in[16];
  const float* c2_b2 = (const float*)d_in[17];
  const float* poolw = (const float*)d_in[18];

  // ---- workspace layout ----
  float* ws = (float*)d_ws;
  float* x1   = ws;                         // 16N
  float* h1   = ws + (size_t)16 * N;        // 32N
  float* o1   = ws + (size_t)48 * N;        // 16N
  float* res2 = ws;                         // 64N (after x1/h1/o1 dead)
  float* x2   = ws + (size_t)64 * N;        // 64N (res1 uses this region first)
  float* res1 = x2;                         // 16N (dead before lin<16,64> writes x2)
  float* h2   = ws + (size_t)128 * N;       // 128N
  float* o2   = ws + (size_t)256 * N;       // 64N
  float* scores = ws + (size_t)320 * N;     // N
  u64* candA = (u64*)(ws + (size_t)321 * N);            // N
  u64* candB = candA + N;                               // N
  u64* sel   = candB + N;                               // 512
  double* partial = (double*)(sel + TOPK);              // STATNB * 256 doubles (2 MB)
  int* ibase   = (int*)(partial + (size_t)STATNB * 256);
  int* istate  = ibase;            // 8
  int* hist    = ibase + 8;        // 256
  int* bsum    = ibase + 264;      // 512
  int* deg     = ibase + 776;      // N
  int* rowstart= deg + N;          // N
  int* cursor  = rowstart + N;     // N
  int* eidx    = cursor + N;       // E
  float* fsc   = (float*)(eidx + E);
  float* sc1 = fsc;        float* sh1 = fsc + 32;
  float* sc2 = fsc + 64;   float* sh2 = fsc + 192;     // 320 floats total

  const int nbN = (N + BLK - 1) / BLK;
  const int nbE = (E + BLK - 1) / BLK;

  // replay-safe zeroing: istate/hist/deg are atomic accumulation targets
  hipMemsetAsync(ibase, 0, (size_t)(776 + N) * sizeof(int), stream);

  // ---- CSR build (shared by both convs) ----
  deg_kernel<<<nbE, BLK, 0, stream>>>(dst, deg, E);
  blocksum_kernel<<<nbN, BLK, 0, stream>>>(deg, bsum, N);
  scanb_kernel<<<1, 512, 0, stream>>>(bsum, nbN);
  rowstart_kernel<<<nbN, BLK, 0, stream>>>(deg, bsum, rowstart, cursor, N);
  scatter_kernel<<<nbE, BLK, 0, stream>>>(src, dst, cursor, eidx, E);

  // ---- conv1 ----
  lin_kernel<3, 16, 16><<<dim3(nbN, 1), BLK, 0, stream>>>(pos, c1_lw, c1_lb, x1, N);
  agg_kernel<16><<<(N * 16 + BLK - 1) / BLK, BLK, 0, stream>>>(rowstart, deg, eidx, x1, res1, N);
  lin_kernel<16, 32, 32><<<dim3(nbN, 1), BLK, 0, stream>>>(res1, c1_w1, c1_b1, h1, N);
  stat_kernel<32><<<STATNB, BLK, 0, stream>>>(h1, partial, N);
  bn_fin2<32><<<32, 256, 0, stream>>>(partial, c1_g1, c1_be1, sc1, sh1, N);
  mlp2_kernel<32, 16, 16><<<dim3(nbN, 1), BLK, 0, stream>>>(h1, sc1, sh1, c1_w2, c1_b2, o1, N);

  // ---- conv2 ----
  lin_kernel<16, 64, 32><<<dim3(nbN, 2), BLK, 0, stream>>>(o1, c2_lw, c2_lb, x2, N);
  agg_kernel<64><<<(N * 64 + BLK - 1) / BLK, BLK, 0, stream>>>(rowstart, deg, eidx, x2, res2, N);
  lin_kernel<64, 128, 32><<<dim3(nbN, 4), BLK, 0, stream>>>(res2, c2_w1, c2_b1, h2, N);
  stat_kernel<128><<<STATNB, BLK, 0, stream>>>(h2, partial, N);
  bn_fin2<128><<<128, 256, 0, stream>>>(partial, c2_g1, c2_be1, sc2, sh2, N);
  mlp2_kernel<128, 64, 32><<<dim3(nbN, 2), BLK, 0, stream>>>(h2, sc2, sh2, c2_w2, c2_b2, o2, N);

  // ---- scores + exact top-K ----
  score_kernel<<<nbN, BLK, 0, stream>>>(o2, poolw, scores, candA, hist, N);
  pick0_kernel<<<1, 64, 0, stream>>>(istate, hist);
  compact0_kernel<<<nbN, BLK, 0, stream>>>(candA, candB, sel, istate, N);
  topk_finish<<<1, 1024, 0, stream>>>(candB, candA, sel, istate, scores, o2, (float*)d_out);

  (void)n_in; (void)out_size; (void)ws_size;
}

// Round 8
// 518.705 us; speedup vs baseline: 1.3621x; 1.0546x over previous
//
#include <hip/hip_runtime.h>
#include <stdint.h>

#define BLK 256

static constexpr float F_EPS = 1e-7f;   // GENConv message eps
static constexpr float F_NEG = 0.01f;   // LeakyReLU slope
static constexpr int   TOPK  = 512;
static constexpr int   STATNB = 1024;   // stat_kernel grid (fixed, partial slots)
static constexpr int   NPART = 8;       // dst-range partitions (== #XCDs)
static constexpr int   PBLK  = 128;     // blocks per partition

typedef unsigned long long u64;

__device__ __forceinline__ unsigned int ord_f32(float f) {
  unsigned int u = __float_as_uint(f);
  return (u & 0x80000000u) ? ~u : (u | 0x80000000u);
}

// ------- dense: out[n, j0:j0+JT] = in[n,:CIN] @ W[:, j0:j0+JT] + b -------
template<int CIN, int COUT, int JT>
__global__ __launch_bounds__(BLK) void lin_kernel(const float* __restrict__ in,
    const float* __restrict__ W, const float* __restrict__ b,
    float* __restrict__ out, int n) {
  __shared__ float sW[CIN * JT];
  __shared__ float sB[JT];
  const int j0 = blockIdx.y * JT;
  for (int i = threadIdx.x; i < CIN * JT; i += BLK) {
    int k = i / JT, jj = i - k * JT;
    sW[i] = W[k * COUT + j0 + jj];
  }
  for (int i = threadIdx.x; i < JT; i += BLK) sB[i] = b[j0 + i];
  __syncthreads();
  int node = blockIdx.x * BLK + threadIdx.x;
  if (node >= n) return;
  float acc[JT];
  #pragma unroll
  for (int jj = 0; jj < JT; ++jj) acc[jj] = sB[jj];
  const float* xrow = in + (size_t)node * CIN;
  if constexpr ((CIN & 3) == 0) {
    constexpr int KC = (CIN > 32) ? 32 : CIN;
    #pragma unroll
    for (int kc = 0; kc < CIN; kc += KC) {
      float x[KC];
      #pragma unroll
      for (int k4 = 0; k4 < KC / 4; ++k4) {
        float4 v = *reinterpret_cast<const float4*>(xrow + kc + k4 * 4);
        x[4*k4+0] = v.x; x[4*k4+1] = v.y; x[4*k4+2] = v.z; x[4*k4+3] = v.w;
      }
      #pragma unroll
      for (int k = 0; k < KC; ++k) {
        #pragma unroll
        for (int jj = 0; jj < JT; ++jj)
          acc[jj] += x[k] * sW[(kc + k) * JT + jj];
      }
    }
  } else {
    #pragma unroll
    for (int k = 0; k < CIN; ++k) {
      float xv = xrow[k];
      #pragma unroll
      for (int jj = 0; jj < JT; ++jj)
        acc[jj] += xv * sW[k * JT + jj];
    }
  }
  float* orow = out + (size_t)node * COUT + j0;
  #pragma unroll
  for (int jj = 0; jj < JT; jj += 4) {
    float4 r; r.x = acc[jj]; r.y = acc[jj+1]; r.z = acc[jj+2]; r.w = acc[jj+3];
    *reinterpret_cast<float4*>(orow + jj) = r;
  }
}

// ---- MLP second half: t=relu(h*scale+shift); out[, j-tile]=leaky(t@W+b) ----
template<int CIN, int COUT, int JT>
__global__ __launch_bounds__(BLK) void mlp2_kernel(const float* __restrict__ h,
    const float* __restrict__ scale, const float* __restrict__ shift,
    const float* __restrict__ W, const float* __restrict__ b,
    float* __restrict__ out, int n) {
  __shared__ float sW[CIN * JT];
  __shared__ float sB[JT];
  __shared__ float sSc[CIN];
  __shared__ float sSh[CIN];
  const int j0 = blockIdx.y * JT;
  for (int i = threadIdx.x; i < CIN * JT; i += BLK) {
    int k = i / JT, jj = i - k * JT;
    sW[i] = W[k * COUT + j0 + jj];
  }
  for (int i = threadIdx.x; i < JT; i += BLK) sB[i] = b[j0 + i];
  for (int i = threadIdx.x; i < CIN; i += BLK) { sSc[i] = scale[i]; sSh[i] = shift[i]; }
  __syncthreads();
  int node = blockIdx.x * BLK + threadIdx.x;
  if (node >= n) return;
  float acc[JT];
  #pragma unroll
  for (int jj = 0; jj < JT; ++jj) acc[jj] = sB[jj];
  const float* xrow = h + (size_t)node * CIN;
  constexpr int KC = (CIN > 32) ? 32 : CIN;
  #pragma unroll
  for (int kc = 0; kc < CIN; kc += KC) {
    float x[KC];
    #pragma unroll
    for (int k4 = 0; k4 < KC / 4; ++k4) {
      float4 v = *reinterpret_cast<const float4*>(xrow + kc + k4 * 4);
      x[4*k4+0] = fmaxf(v.x * sSc[kc+4*k4+0] + sSh[kc+4*k4+0], 0.f);
      x[4*k4+1] = fmaxf(v.y * sSc[kc+4*k4+1] + sSh[kc+4*k4+1], 0.f);
      x[4*k4+2] = fmaxf(v.z * sSc[kc+4*k4+2] + sSh[kc+4*k4+2], 0.f);
      x[4*k4+3] = fmaxf(v.w * sSc[kc+4*k4+3] + sSh[kc+4*k4+3], 0.f);
    }
    #pragma unroll
    for (int k = 0; k < KC; ++k) {
      #pragma unroll
      for (int jj = 0; jj < JT; ++jj)
        acc[jj] += x[k] * sW[(kc + k) * JT + jj];
    }
  }
  float* orow = out + (size_t)node * COUT + j0;
  #pragma unroll
  for (int jj = 0; jj < JT; jj += 4) {
    float a0 = acc[jj], a1 = acc[jj+1], a2 = acc[jj+2], a3 = acc[jj+3];
    a0 = a0 > 0.f ? a0 : F_NEG * a0;
    a1 = a1 > 0.f ? a1 : F_NEG * a1;
    a2 = a2 > 0.f ? a2 : F_NEG * a2;
    a3 = a3 > 0.f ? a3 : F_NEG * a3;
    float4 r; r.x = a0; r.y = a1; r.z = a2; r.w = a3;
    *reinterpret_cast<float4*>(orow + jj) = r;
  }
}

// ---------------- CSR build (XCD-partitioned by dst range) ----------------
// partition id dr = d*NPART/n  (contiguous dst ranges). Block with
// blockIdx&7==r processes only range r; under round-robin block->XCD
// dispatch all of range r's writes come from one XCD -> lines fill fully
// before writeback. Correctness does NOT depend on the mapping.
__global__ __launch_bounds__(BLK) void deg_kernel(const int* __restrict__ dst,
    int* __restrict__ deg, int E, int n) {
  const int r = blockIdx.x & (NPART - 1);
  const int sb = blockIdx.x >> 3;
  const int nsb = gridDim.x >> 3;
  for (int e = sb * BLK + threadIdx.x; e < E; e += nsb * BLK) {
    int d = dst[e];
    int dr = (int)(((unsigned long long)(unsigned)d * NPART) / (unsigned)n);
    if (dr == r) atomicAdd(&deg[d], 1);
  }
}

__global__ __launch_bounds__(BLK) void blocksum_kernel(const int* __restrict__ deg,
    int* __restrict__ bsum, int n) {
  int i = blockIdx.x * BLK + threadIdx.x;
  int v = (i < n) ? deg[i] : 0;
  for (int off = 32; off; off >>= 1) v += __shfl_down(v, off);
  __shared__ int wsum[4];
  int lane = threadIdx.x & 63, wid = threadIdx.x >> 6;
  if (lane == 0) wsum[wid] = v;
  __syncthreads();
  if (threadIdx.x == 0) bsum[blockIdx.x] = wsum[0] + wsum[1] + wsum[2] + wsum[3];
}

__global__ __launch_bounds__(512) void scanb_kernel(int* __restrict__ bsum, int nb) {
  __shared__ int s[512];
  int t = threadIdx.x;
  int orig = (t < nb) ? bsum[t] : 0;
  s[t] = orig;
  __syncthreads();
  for (int off = 1; off < 512; off <<= 1) {
    int add = (t >= off) ? s[t - off] : 0;
    __syncthreads();
    s[t] += add;
    __syncthreads();
  }
  if (t < nb) bsum[t] = s[t] - orig;   // exclusive
}

__global__ __launch_bounds__(BLK) void rowstart_kernel(const int* __restrict__ deg,
    const int* __restrict__ bsum, int* __restrict__ rowstart,
    int* __restrict__ cursor, int n) {
  __shared__ int s[BLK];
  int t = threadIdx.x, i = blockIdx.x * BLK + t;
  int orig = (i < n) ? deg[i] : 0;
  s[t] = orig;
  __syncthreads();
  for (int off = 1; off < BLK; off <<= 1) {
    int add = (t >= off) ? s[t - off] : 0;
    __syncthreads();
    s[t] += add;
    __syncthreads();
  }
  if (i < n) { int st = bsum[blockIdx.x] + s[t] - orig; rowstart[i] = st; cursor[i] = st; }
}

__global__ __launch_bounds__(BLK) void scatter_kernel(const int* __restrict__ src,
    const int* __restrict__ dst, int* __restrict__ cursor, int* __restrict__ eidx,
    int E, int n) {
  const int r = blockIdx.x & (NPART - 1);
  const int sb = blockIdx.x >> 3;
  const int nsb = gridDim.x >> 3;
  for (int e = sb * BLK + threadIdx.x; e < E; e += nsb * BLK) {
    int d = dst[e];
    int dr = (int)(((unsigned long long)(unsigned)d * NPART) / (unsigned)n);
    if (dr == r) {
      int p = atomicAdd(&cursor[d], 1);
      eidx[p] = src[e];
    }
  }
}

// ---- fused gather-aggregate + residual: out = num/(den+1e-16) + x[d] ----
template<int C>
__global__ __launch_bounds__(BLK) void agg_kernel(const int* __restrict__ rowstart,
    const int* __restrict__ deg, const int* __restrict__ eidx,
    const float* __restrict__ x, float* __restrict__ out, int n) {
  int gid = blockIdx.x * BLK + threadIdx.x;
  int node = gid / C;
  int c = gid & (C - 1);
  if (node >= n) return;
  int s0 = rowstart[node];
  int d = deg[node];
  float den = 0.f, num = 0.f;
  int j = 0;
  for (; j + 3 < d; j += 4) {
    int sA = eidx[s0 + j], sB = eidx[s0 + j + 1];
    int sC = eidx[s0 + j + 2], sD = eidx[s0 + j + 3];
    float xa = x[(size_t)sA * C + c];
    float xb = x[(size_t)sB * C + c];
    float xc = x[(size_t)sC * C + c];
    float xd = x[(size_t)sD * C + c];
    float ma = fmaxf(xa, 0.f) + F_EPS;
    float mb = fmaxf(xb, 0.f) + F_EPS;
    float mc = fmaxf(xc, 0.f) + F_EPS;
    float md = fmaxf(xd, 0.f) + F_EPS;
    float aa = __expf(ma), ab = __expf(mb), ac = __expf(mc), ad = __expf(md);
    den += (aa + ab) + (ac + ad);
    num += (ma * aa + mb * ab) + (mc * ac + md * ad);
  }
  for (; j < d; ++j) {
    int sA = eidx[s0 + j];
    float xa = x[(size_t)sA * C + c];
    float ma = fmaxf(xa, 0.f) + F_EPS;
    float aa = __expf(ma);
    den += aa;
    num += ma * aa;
  }
  float xd = x[(size_t)node * C + c];
  out[(size_t)node * C + c] = num / (den + 1e-16f) + xd;
}

// ---- BN stats pass 1: per-block f64 partial column sums (NO atomics) ----
template<int COUT>
__global__ __launch_bounds__(BLK) void stat_kernel(const float* __restrict__ h,
    double* __restrict__ partial, int n) {
  constexpr int G = COUT / 4;
  constexpr int REPS = BLK / G;
  double s0 = 0, s1 = 0, s2 = 0, s3 = 0, q0 = 0, q1 = 0, q2 = 0, q3 = 0;
  int total4 = n * G;
  for (int i = blockIdx.x * BLK + threadIdx.x; i < total4; i += gridDim.x * BLK) {
    float4 v = reinterpret_cast<const float4*>(h)[i];
    double dx = v.x, dy = v.y, dz = v.z, dw = v.w;
    s0 += dx; q0 += dx * dx;
    s1 += dy; q1 += dy * dy;
    s2 += dz; q2 += dz * dz;
    s3 += dw; q3 += dw * dw;
  }
  __shared__ double sL[BLK * 8];
  double* my = sL + threadIdx.x * 8;
  my[0] = s0; my[1] = s1; my[2] = s2; my[3] = s3;
  my[4] = q0; my[5] = q1; my[6] = q2; my[7] = q3;
  __syncthreads();
  int g = threadIdx.x;
  if (g < G) {
    for (int r = 1; r < REPS; ++r) {
      double* o = sL + (g + r * G) * 8;
      s0 += o[0]; s1 += o[1]; s2 += o[2]; s3 += o[3];
      q0 += o[4]; q1 += o[5]; q2 += o[6]; q3 += o[7];
    }
    double* prow = partial + (size_t)blockIdx.x * (2 * COUT);
    prow[4*g+0] = s0; prow[4*g+1] = s1; prow[4*g+2] = s2; prow[4*g+3] = s3;
    prow[COUT+4*g+0] = q0; prow[COUT+4*g+1] = q1;
    prow[COUT+4*g+2] = q2; prow[COUT+4*g+3] = q3;
  }
}

// ---- BN stats pass 2: one block per channel reduces STATNB partials ----
template<int COUT>
__global__ __launch_bounds__(256) void bn_fin2(const double* __restrict__ partial,
    const float* __restrict__ g, const float* __restrict__ be,
    float* __restrict__ sc, float* __restrict__ sh, int n) {
  int j = blockIdx.x;
  int t = threadIdx.x;
  double s = 0, q = 0;
  for (int b = t; b < STATNB; b += 256) {
    const double* prow = partial + (size_t)b * (2 * COUT);
    s += prow[j];
    q += prow[COUT + j];
  }
  for (int off = 32; off; off >>= 1) { s += __shfl_down(s, off); q += __shfl_down(q, off); }
  __shared__ double sw[4][2];
  int lane = t & 63, wid = t >> 6;
  if (lane == 0) { sw[wid][0] = s; sw[wid][1] = q; }
  __syncthreads();
  if (t == 0) {
    s = sw[0][0] + sw[1][0] + sw[2][0] + sw[3][0];
    q = sw[0][1] + sw[1][1] + sw[2][1] + sw[3][1];
    double inv_n = 1.0 / (double)n;
    double mu = s * inv_n;
    double var = q * inv_n - mu * mu;
    double scd = (double)g[j] / sqrt(var + 1e-5);
    sc[j] = (float)scd;
    sh[j] = (float)((double)be[j] - mu * scd);
  }
}

// ---- score + key + round-0 histogram (byte 7) ----
__global__ __launch_bounds__(BLK) void score_kernel(const float* __restrict__ x,
    const float* __restrict__ w, float* __restrict__ scores,
    u64* __restrict__ keys, int* __restrict__ ghist, int n) {
  __shared__ float sw[64];
  __shared__ float snorm;
  __shared__ int hl[256];
  if (threadIdx.x < 64) sw[threadIdx.x] = w[threadIdx.x];
  hl[threadIdx.x] = 0;
  __syncthreads();
  if (threadIdx.x < 64) {
    float v = sw[threadIdx.x];
    float sq = v * v;
    for (int off = 32; off; off >>= 1) sq += __shfl_down(sq, off);
    if (threadIdx.x == 0) snorm = 1.f / sqrtf(sq);
  }
  __syncthreads();
  int node = blockIdx.x * BLK + threadIdx.x;
  if (node < n) {
    const float4* row = reinterpret_cast<const float4*>(x + (size_t)node * 64);
    float acc = 0.f;
    #pragma unroll
    for (int k4 = 0; k4 < 16; ++k4) {
      float4 v = row[k4];
      const float4 wv = *reinterpret_cast<const float4*>(&sw[4 * k4]);
      acc += v.x * wv.x + v.y * wv.y + v.z * wv.z + v.w * wv.w;
    }
    float s = tanhf(acc * snorm);
    scores[node] = s;
    u64 key = ((u64)ord_f32(s) << 32) | (unsigned int)(~node);
    keys[node] = key;
    atomicAdd(&hl[(int)(key >> 56)], 1);
  }
  __syncthreads();
  int v = hl[threadIdx.x];
  if (v) atomicAdd(&ghist[threadIdx.x], v);
}

// istate: [0]=k remaining [1]=digit [2]=sel count [4]=out count
__global__ void pick0_kernel(int* __restrict__ istate, const int* __restrict__ hist) {
  if (threadIdx.x == 0) {
    int k = TOPK, run = 0;
    for (int d = 255; d >= 0; --d) {
      int c = hist[d];
      if (run + c >= k) { istate[1] = d; istate[0] = k - run; break; }
      run += c;
    }
    istate[2] = 0; istate[4] = 0;
  }
}

__global__ __launch_bounds__(BLK) void compact0_kernel(const u64* __restrict__ in,
    u64* __restrict__ outb, u64* __restrict__ sel, int* __restrict__ istate, int n) {
  int i = blockIdx.x * BLK + threadIdx.x;
  if (i >= n) return;
  u64 kkey = in[i];
  int b = (int)(kkey >> 56);
  int digit = istate[1];
  if (b > digit) {
    sel[atomicAdd(&istate[2], 1)] = kkey;
  } else if (b == digit) {
    outb[atomicAdd(&istate[4], 1)] = kkey;
  }
}

// ---- single block: radix rounds 1..7 + append + bitonic sort + gather ----
__global__ __launch_bounds__(1024) void topk_finish(u64* __restrict__ bufB,
    u64* __restrict__ bufA, u64* __restrict__ sel, const int* __restrict__ istate,
    const float* __restrict__ scores, const float* __restrict__ x,
    float* __restrict__ out) {
  __shared__ int hl[256];
  __shared__ int sh_digit, sh_k, sh_sel, sh_out, sh_cnt;
  __shared__ u64 sk[512];
  int t = threadIdx.x;
  if (t == 0) { sh_cnt = istate[4]; sh_k = istate[0]; sh_sel = istate[2]; }
  __syncthreads();
  u64* cur = bufB;
  u64* nxt = bufA;
  for (int shift = 48; shift >= 0; shift -= 8) {
    for (int i = t; i < 256; i += 1024) hl[i] = 0;
    __syncthreads();
    int cnt = sh_cnt;
    for (int i = t; i < cnt; i += 1024) atomicAdd(&hl[(int)((cur[i] >> shift) & 255ull)], 1);
    __syncthreads();
    if (t == 0) {
      int k = sh_k, run = 0;
      for (int d = 255; d >= 0; --d) {
        int c = hl[d];
        if (run + c >= k) { sh_digit = d; sh_k = k - run; break; }
        run += c;
      }
      sh_out = 0;
    }
    __syncthreads();
    int digit = sh_digit;
    for (int i = t; i < cnt; i += 1024) {
      u64 kk = cur[i];
      int b = (int)((kk >> shift) & 255ull);
      if (b > digit) sel[atomicAdd(&sh_sel, 1)] = kk;
      else if (b == digit) nxt[atomicAdd(&sh_out, 1)] = kk;
    }
    __syncthreads();
    if (t == 0) sh_cnt = sh_out;
    __syncthreads();
    u64* tmp = cur; cur = nxt; nxt = tmp;
  }
  int base = sh_sel, krem = sh_k;
  for (int i = t; i < krem; i += 1024) sel[base + i] = cur[i];
  __syncthreads();
  if (t < 512) sk[t] = sel[t];
  __syncthreads();
  for (int k = 2; k <= 512; k <<= 1) {
    for (int j = k >> 1; j > 0; j >>= 1) {
      if (t < 512) {
        int ixj = t ^ j;
        if (ixj > t) {
          bool dirDesc = ((t & k) == 0);
          u64 A = sk[t], B = sk[ixj];
          bool swp = dirDesc ? (A < B) : (A > B);
          if (swp) { sk[t] = B; sk[ixj] = A; }
        }
      }
      __syncthreads();
    }
  }
  for (int i = t; i < 512 * 16; i += 1024) {
    int r = i >> 4, c = i & 15;
    u64 kk = sk[r];
    int nidx = (int)(~(unsigned int)(kk & 0xffffffffull));
    float v = scores[nidx];
    float4 xv = reinterpret_cast<const float4*>(x)[(size_t)nidx * 16 + c];
    float4 r4; r4.x = xv.x * v; r4.y = xv.y * v; r4.z = xv.z * v; r4.w = xv.w * v;
    reinterpret_cast<float4*>(out)[(size_t)r * 16 + c] = r4;
  }
}

extern "C" void kernel_launch(void* const* d_in, const int* in_sizes, int n_in,
                              void* d_out, int out_size, void* d_ws, size_t ws_size,
                              hipStream_t stream) {
  const int N = in_sizes[0] / 3;
  const int E = in_sizes[1] / 2;

  const float* pos   = (const float*)d_in[0];
  const int*   ei    = (const int*)d_in[1];
  const int*   src   = ei;
  const int*   dst   = ei + E;
  const float* c1_lw = (const float*)d_in[2];
  const float* c1_lb = (const float*)d_in[3];
  const float* c1_w1 = (const float*)d_in[4];
  const float* c1_b1 = (const float*)d_in[5];
  const float* c1_g1 = (const float*)d_in[6];
  const float* c1_be1= (const float*)d_in[7];
  const float* c1_w2 = (const float*)d_in[8];
  const float* c1_b2 = (const float*)d_in[9];
  const float* c2_lw = (const float*)d_in[10];
  const float* c2_lb = (const float*)d_in[11];
  const float* c2_w1 = (const float*)d_in[12];
  const float* c2_b1 = (const float*)d_in[13];
  const float* c2_g1 = (const float*)d_in[14];
  const float* c2_be1= (const float*)d_in[15];
  const float* c2_w2 = (const float*)d_in[16];
  const float* c2_b2 = (const float*)d_in[17];
  const float* poolw = (const float*)d_in[18];

  // ---- workspace layout ----
  float* ws = (float*)d_ws;
  float* x1   = ws;                         // 16N
  float* h1   = ws + (size_t)16 * N;        // 32N
  float* o1   = ws + (size_t)48 * N;        // 16N
  float* res2 = ws;                         // 64N (after x1/h1/o1 dead)
  float* x2   = ws + (size_t)64 * N;        // 64N (res1 uses this region first)
  float* res1 = x2;                         // 16N (dead before lin<16,64> writes x2)
  float* h2   = ws + (size_t)128 * N;       // 128N
  float* o2   = ws + (size_t)256 * N;       // 64N
  float* scores = ws + (size_t)320 * N;     // N
  u64* candA = (u64*)(ws + (size_t)321 * N);            // N
  u64* candB = candA + N;                               // N
  u64* sel   = candB + N;                               // 512
  double* partial = (double*)(sel + TOPK);              // STATNB * 256 doubles (2 MB)
  int* ibase   = (int*)(partial + (size_t)STATNB * 256);
  int* istate  = ibase;            // 8
  int* hist    = ibase + 8;        // 256
  int* bsum    = ibase + 264;      // 512
  int* deg     = ibase + 776;      // N
  int* rowstart= deg + N;          // N
  int* cursor  = rowstart + N;     // N
  int* eidx    = cursor + N;       // E
  float* fsc   = (float*)(eidx + E);
  float* sc1 = fsc;        float* sh1 = fsc + 32;
  float* sc2 = fsc + 64;   float* sh2 = fsc + 192;     // 320 floats total

  const int nbN = (N + BLK - 1) / BLK;

  // replay-safe zeroing: istate/hist/deg are atomic accumulation targets
  hipMemsetAsync(ibase, 0, (size_t)(776 + N) * sizeof(int), stream);

  // ---- CSR build (shared by both convs) ----
  deg_kernel<<<NPART * PBLK, BLK, 0, stream>>>(dst, deg, E, N);
  blocksum_kernel<<<nbN, BLK, 0, stream>>>(deg, bsum, N);
  scanb_kernel<<<1, 512, 0, stream>>>(bsum, nbN);
  rowstart_kernel<<<nbN, BLK, 0, stream>>>(deg, bsum, rowstart, cursor, N);
  scatter_kernel<<<NPART * PBLK, BLK, 0, stream>>>(src, dst, cursor, eidx, E, N);

  // ---- conv1 ----
  lin_kernel<3, 16, 16><<<dim3(nbN, 1), BLK, 0, stream>>>(pos, c1_lw, c1_lb, x1, N);
  agg_kernel<16><<<(N * 16 + BLK - 1) / BLK, BLK, 0, stream>>>(rowstart, deg, eidx, x1, res1, N);
  lin_kernel<16, 32, 32><<<dim3(nbN, 1), BLK, 0, stream>>>(res1, c1_w1, c1_b1, h1, N);
  stat_kernel<32><<<STATNB, BLK, 0, stream>>>(h1, partial, N);
  bn_fin2<32><<<32, 256, 0, stream>>>(partial, c1_g1, c1_be1, sc1, sh1, N);
  mlp2_kernel<32, 16, 16><<<dim3(nbN, 1), BLK, 0, stream>>>(h1, sc1, sh1, c1_w2, c1_b2, o1, N);

  // ---- conv2 ----
  lin_kernel<16, 64, 32><<<dim3(nbN, 2), BLK, 0, stream>>>(o1, c2_lw, c2_lb, x2, N);
  agg_kernel<64><<<(N * 64 + BLK - 1) / BLK, BLK, 0, stream>>>(rowstart, deg, eidx, x2, res2, N);
  lin_kernel<64, 128, 32><<<dim3(nbN, 4), BLK, 0, stream>>>(res2, c2_w1, c2_b1, h2, N);
  stat_kernel<128><<<STATNB, BLK, 0, stream>>>(h2, partial, N);
  bn_fin2<128><<<128, 256, 0, stream>>>(partial, c2_g1, c2_be1, sc2, sh2, N);
  mlp2_kernel<128, 64, 32><<<dim3(nbN, 2), BLK, 0, stream>>>(h2, sc2, sh2, c2_w2, c2_b2, o2, N);

  // ---- scores + exact top-K ----
  score_kernel<<<nbN, BLK, 0, stream>>>(o2, poolw, scores, candA, hist, N);
  pick0_kernel<<<1, 64, 0, stream>>>(istate, hist);
  compact0_kernel<<<nbN, BLK, 0, stream>>>(candA, candB, sel, istate, N);
  topk_finish<<<1, 1024, 0, stream>>>(candB, candA, sel, istate, scores, o2, (float*)d_out);

  (void)n_in; (void)out_size; (void)ws_size;
}

// Round 9
// 514.127 us; speedup vs baseline: 1.3742x; 1.0089x over previous
//
#include <hip/hip_runtime.h>
#include <stdint.h>

#define BLK 256

static constexpr float F_EPS = 1e-7f;   // GENConv message eps
static constexpr float F_NEG = 0.01f;   // LeakyReLU slope
static constexpr int   TOPK  = 512;
static constexpr int   NPART = 8;       // dst-range partitions (== #XCDs)
static constexpr int   PBLK  = 128;     // blocks per partition

typedef unsigned long long u64;

__device__ __forceinline__ unsigned int ord_f32(float f) {
  unsigned int u = __float_as_uint(f);
  return (u & 0x80000000u) ? ~u : (u | 0x80000000u);
}

// ------- dense: out[n, j0:j0+JT] = in[n,:CIN] @ W[:, j0:j0+JT] + b -------
// STAT: additionally emit per-block f64 column sums/sumsqs of the outputs
// (for train-mode BatchNorm) into partial[(blockIdx.y*gridDim.x+blockIdx.x)].
template<int CIN, int COUT, int JT, bool STAT = false>
__global__ __launch_bounds__(BLK) void lin_kernel(const float* __restrict__ in,
    const float* __restrict__ W, const float* __restrict__ b,
    float* __restrict__ out, double* __restrict__ partial, int n) {
  __shared__ float sW[CIN * JT];
  __shared__ float sB[JT];
  const int j0 = blockIdx.y * JT;
  for (int i = threadIdx.x; i < CIN * JT; i += BLK) {
    int k = i / JT, jj = i - k * JT;
    sW[i] = W[k * COUT + j0 + jj];
  }
  for (int i = threadIdx.x; i < JT; i += BLK) sB[i] = b[j0 + i];
  __syncthreads();
  int node = blockIdx.x * BLK + threadIdx.x;
  bool valid = node < n;
  if constexpr (!STAT) { if (!valid) return; }
  int rnode = valid ? node : (n - 1);
  float acc[JT];
  #pragma unroll
  for (int jj = 0; jj < JT; ++jj) acc[jj] = sB[jj];
  const float* xrow = in + (size_t)rnode * CIN;
  if constexpr ((CIN & 3) == 0) {
    constexpr int KC = (CIN > 32) ? 32 : CIN;
    #pragma unroll
    for (int kc = 0; kc < CIN; kc += KC) {
      float x[KC];
      #pragma unroll
      for (int k4 = 0; k4 < KC / 4; ++k4) {
        float4 v = *reinterpret_cast<const float4*>(xrow + kc + k4 * 4);
        x[4*k4+0] = v.x; x[4*k4+1] = v.y; x[4*k4+2] = v.z; x[4*k4+3] = v.w;
      }
      #pragma unroll
      for (int k = 0; k < KC; ++k) {
        #pragma unroll
        for (int jj = 0; jj < JT; ++jj)
          acc[jj] += x[k] * sW[(kc + k) * JT + jj];
      }
    }
  } else {
    #pragma unroll
    for (int k = 0; k < CIN; ++k) {
      float xv = xrow[k];
      #pragma unroll
      for (int jj = 0; jj < JT; ++jj)
        acc[jj] += xv * sW[k * JT + jj];
    }
  }
  if (valid) {
    float* orow = out + (size_t)node * COUT + j0;
    #pragma unroll
    for (int jj = 0; jj < JT; jj += 4) {
      float4 r; r.x = acc[jj]; r.y = acc[jj+1]; r.z = acc[jj+2]; r.w = acc[jj+3];
      *reinterpret_cast<float4*>(orow + jj) = r;
    }
  }
  if constexpr (STAT) {
    __shared__ double sStat[4][2 * JT];
    int lane = threadIdx.x & 63, wid = threadIdx.x >> 6;
    #pragma unroll
    for (int jj = 0; jj < JT; ++jj) {
      double sv = valid ? (double)acc[jj] : 0.0;
      double qv = sv * sv;
      for (int off = 32; off; off >>= 1) {
        sv += __shfl_down(sv, off);
        qv += __shfl_down(qv, off);
      }
      if (lane == 0) { sStat[wid][jj] = sv; sStat[wid][JT + jj] = qv; }
    }
    __syncthreads();
    if (threadIdx.x < 2 * JT) {
      double v = sStat[0][threadIdx.x] + sStat[1][threadIdx.x]
               + sStat[2][threadIdx.x] + sStat[3][threadIdx.x];
      partial[((size_t)blockIdx.y * gridDim.x + blockIdx.x) * (2 * JT) + threadIdx.x] = v;
    }
  }
}

// ---- BN finalize: one block per channel reduces per-block partials ----
template<int COUT, int JT>
__global__ __launch_bounds__(256) void bn_fin3(const double* __restrict__ partial,
    const float* __restrict__ g, const float* __restrict__ be,
    float* __restrict__ sc, float* __restrict__ sh, int n, int nbx) {
  int j = blockIdx.x;
  int t = threadIdx.x;
  int jt = j / JT, jj = j - jt * JT;
  double s = 0, q = 0;
  for (int b = t; b < nbx; b += 256) {
    const double* row = partial + ((size_t)jt * nbx + b) * (2 * JT);
    s += row[jj];
    q += row[JT + jj];
  }
  for (int off = 32; off; off >>= 1) { s += __shfl_down(s, off); q += __shfl_down(q, off); }
  __shared__ double sw[4][2];
  int lane = t & 63, wid = t >> 6;
  if (lane == 0) { sw[wid][0] = s; sw[wid][1] = q; }
  __syncthreads();
  if (t == 0) {
    s = sw[0][0] + sw[1][0] + sw[2][0] + sw[3][0];
    q = sw[0][1] + sw[1][1] + sw[2][1] + sw[3][1];
    double inv_n = 1.0 / (double)n;
    double mu = s * inv_n;
    double var = q * inv_n - mu * mu;
    double scd = (double)g[j] / sqrt(var + 1e-5);
    sc[j] = (float)scd;
    sh[j] = (float)((double)be[j] - mu * scd);
  }
}

// ---- MLP second half: t=relu(h*scale+shift); out[, j-tile]=leaky(t@W+b) ----
template<int CIN, int COUT, int JT>
__global__ __launch_bounds__(BLK) void mlp2_kernel(const float* __restrict__ h,
    const float* __restrict__ scale, const float* __restrict__ shift,
    const float* __restrict__ W, const float* __restrict__ b,
    float* __restrict__ out, int n) {
  __shared__ float sW[CIN * JT];
  __shared__ float sB[JT];
  __shared__ float sSc[CIN];
  __shared__ float sSh[CIN];
  const int j0 = blockIdx.y * JT;
  for (int i = threadIdx.x; i < CIN * JT; i += BLK) {
    int k = i / JT, jj = i - k * JT;
    sW[i] = W[k * COUT + j0 + jj];
  }
  for (int i = threadIdx.x; i < JT; i += BLK) sB[i] = b[j0 + i];
  for (int i = threadIdx.x; i < CIN; i += BLK) { sSc[i] = scale[i]; sSh[i] = shift[i]; }
  __syncthreads();
  int node = blockIdx.x * BLK + threadIdx.x;
  if (node >= n) return;
  float acc[JT];
  #pragma unroll
  for (int jj = 0; jj < JT; ++jj) acc[jj] = sB[jj];
  const float* xrow = h + (size_t)node * CIN;
  constexpr int KC = (CIN > 32) ? 32 : CIN;
  #pragma unroll
  for (int kc = 0; kc < CIN; kc += KC) {
    float x[KC];
    #pragma unroll
    for (int k4 = 0; k4 < KC / 4; ++k4) {
      float4 v = *reinterpret_cast<const float4*>(xrow + kc + k4 * 4);
      x[4*k4+0] = fmaxf(v.x * sSc[kc+4*k4+0] + sSh[kc+4*k4+0], 0.f);
      x[4*k4+1] = fmaxf(v.y * sSc[kc+4*k4+1] + sSh[kc+4*k4+1], 0.f);
      x[4*k4+2] = fmaxf(v.z * sSc[kc+4*k4+2] + sSh[kc+4*k4+2], 0.f);
      x[4*k4+3] = fmaxf(v.w * sSc[kc+4*k4+3] + sSh[kc+4*k4+3], 0.f);
    }
    #pragma unroll
    for (int k = 0; k < KC; ++k) {
      #pragma unroll
      for (int jj = 0; jj < JT; ++jj)
        acc[jj] += x[k] * sW[(kc + k) * JT + jj];
    }
  }
  float* orow = out + (size_t)node * COUT + j0;
  #pragma unroll
  for (int jj = 0; jj < JT; jj += 4) {
    float a0 = acc[jj], a1 = acc[jj+1], a2 = acc[jj+2], a3 = acc[jj+3];
    a0 = a0 > 0.f ? a0 : F_NEG * a0;
    a1 = a1 > 0.f ? a1 : F_NEG * a1;
    a2 = a2 > 0.f ? a2 : F_NEG * a2;
    a3 = a3 > 0.f ? a3 : F_NEG * a3;
    float4 r; r.x = a0; r.y = a1; r.z = a2; r.w = a3;
    *reinterpret_cast<float4*>(orow + jj) = r;
  }
}

// ---------------- CSR build (XCD-partitioned by dst range) ----------------
__global__ __launch_bounds__(BLK) void deg_kernel(const int* __restrict__ dst,
    int* __restrict__ deg, int E, int n) {
  const int r = blockIdx.x & (NPART - 1);
  const int sb = blockIdx.x >> 3;
  const int nsb = gridDim.x >> 3;
  for (int e = sb * BLK + threadIdx.x; e < E; e += nsb * BLK) {
    int d = dst[e];
    int dr = (int)(((unsigned long long)(unsigned)d * NPART) / (unsigned)n);
    if (dr == r) atomicAdd(&deg[d], 1);
  }
}

__global__ __launch_bounds__(BLK) void blocksum_kernel(const int* __restrict__ deg,
    int* __restrict__ bsum, int n) {
  int i = blockIdx.x * BLK + threadIdx.x;
  int v = (i < n) ? deg[i] : 0;
  for (int off = 32; off; off >>= 1) v += __shfl_down(v, off);
  __shared__ int wsum[4];
  int lane = threadIdx.x & 63, wid = threadIdx.x >> 6;
  if (lane == 0) wsum[wid] = v;
  __syncthreads();
  if (threadIdx.x == 0) bsum[blockIdx.x] = wsum[0] + wsum[1] + wsum[2] + wsum[3];
}

__global__ __launch_bounds__(512) void scanb_kernel(int* __restrict__ bsum, int nb) {
  __shared__ int s[512];
  int t = threadIdx.x;
  int orig = (t < nb) ? bsum[t] : 0;
  s[t] = orig;
  __syncthreads();
  for (int off = 1; off < 512; off <<= 1) {
    int add = (t >= off) ? s[t - off] : 0;
    __syncthreads();
    s[t] += add;
    __syncthreads();
  }
  if (t < nb) bsum[t] = s[t] - orig;   // exclusive
}

__global__ __launch_bounds__(BLK) void rowstart_kernel(const int* __restrict__ deg,
    const int* __restrict__ bsum, int* __restrict__ rowstart,
    int* __restrict__ cursor, int n) {
  __shared__ int s[BLK];
  int t = threadIdx.x, i = blockIdx.x * BLK + t;
  int orig = (i < n) ? deg[i] : 0;
  s[t] = orig;
  __syncthreads();
  for (int off = 1; off < BLK; off <<= 1) {
    int add = (t >= off) ? s[t - off] : 0;
    __syncthreads();
    s[t] += add;
    __syncthreads();
  }
  if (i < n) { int st = bsum[blockIdx.x] + s[t] - orig; rowstart[i] = st; cursor[i] = st; }
}

__global__ __launch_bounds__(BLK) void scatter_kernel(const int* __restrict__ src,
    const int* __restrict__ dst, int* __restrict__ cursor, int* __restrict__ eidx,
    int E, int n) {
  const int r = blockIdx.x & (NPART - 1);
  const int sb = blockIdx.x >> 3;
  const int nsb = gridDim.x >> 3;
  for (int e = sb * BLK + threadIdx.x; e < E; e += nsb * BLK) {
    int d = dst[e];
    int dr = (int)(((unsigned long long)(unsigned)d * NPART) / (unsigned)n);
    if (dr == r) {
      int p = atomicAdd(&cursor[d], 1);
      eidx[p] = src[e];
    }
  }
}

// ---- fused gather-aggregate + residual: out = num/(den+1e-16) + x[d] ----
template<int C>
__global__ __launch_bounds__(BLK) void agg_kernel(const int* __restrict__ rowstart,
    const int* __restrict__ deg, const int* __restrict__ eidx,
    const float* __restrict__ x, float* __restrict__ out, int n) {
  int gid = blockIdx.x * BLK + threadIdx.x;
  int node = gid / C;
  int c = gid & (C - 1);
  if (node >= n) return;
  int s0 = rowstart[node];
  int d = deg[node];
  float den = 0.f, num = 0.f;
  int j = 0;
  for (; j + 3 < d; j += 4) {
    int sA = eidx[s0 + j], sB = eidx[s0 + j + 1];
    int sC = eidx[s0 + j + 2], sD = eidx[s0 + j + 3];
    float xa = x[(size_t)sA * C + c];
    float xb = x[(size_t)sB * C + c];
    float xc = x[(size_t)sC * C + c];
    float xd = x[(size_t)sD * C + c];
    float ma = fmaxf(xa, 0.f) + F_EPS;
    float mb = fmaxf(xb, 0.f) + F_EPS;
    float mc = fmaxf(xc, 0.f) + F_EPS;
    float md = fmaxf(xd, 0.f) + F_EPS;
    float aa = __expf(ma), ab = __expf(mb), ac = __expf(mc), ad = __expf(md);
    den += (aa + ab) + (ac + ad);
    num += (ma * aa + mb * ab) + (mc * ac + md * ad);
  }
  for (; j < d; ++j) {
    int sA = eidx[s0 + j];
    float xa = x[(size_t)sA * C + c];
    float ma = fmaxf(xa, 0.f) + F_EPS;
    float aa = __expf(ma);
    den += aa;
    num += ma * aa;
  }
  float xd = x[(size_t)node * C + c];
  out[(size_t)node * C + c] = num / (den + 1e-16f) + xd;
}

// ---- score + key + round-0 histogram (byte 7) ----
__global__ __launch_bounds__(BLK) void score_kernel(const float* __restrict__ x,
    const float* __restrict__ w, float* __restrict__ scores,
    u64* __restrict__ keys, int* __restrict__ ghist, int n) {
  __shared__ float sw[64];
  __shared__ float snorm;
  __shared__ int hl[256];
  if (threadIdx.x < 64) sw[threadIdx.x] = w[threadIdx.x];
  hl[threadIdx.x] = 0;
  __syncthreads();
  if (threadIdx.x < 64) {
    float v = sw[threadIdx.x];
    float sq = v * v;
    for (int off = 32; off; off >>= 1) sq += __shfl_down(sq, off);
    if (threadIdx.x == 0) snorm = 1.f / sqrtf(sq);
  }
  __syncthreads();
  int node = blockIdx.x * BLK + threadIdx.x;
  if (node < n) {
    const float4* row = reinterpret_cast<const float4*>(x + (size_t)node * 64);
    float acc = 0.f;
    #pragma unroll
    for (int k4 = 0; k4 < 16; ++k4) {
      float4 v = row[k4];
      const float4 wv = *reinterpret_cast<const float4*>(&sw[4 * k4]);
      acc += v.x * wv.x + v.y * wv.y + v.z * wv.z + v.w * wv.w;
    }
    float s = tanhf(acc * snorm);
    scores[node] = s;
    u64 key = ((u64)ord_f32(s) << 32) | (unsigned int)(~node);
    keys[node] = key;
    atomicAdd(&hl[(int)(key >> 56)], 1);
  }
  __syncthreads();
  int v = hl[threadIdx.x];
  if (v) atomicAdd(&ghist[threadIdx.x], v);
}

// istate: [0]=k remaining [1]=digit [2]=sel count [4]=out count
__global__ void pick0_kernel(int* __restrict__ istate, const int* __restrict__ hist) {
  if (threadIdx.x == 0) {
    int k = TOPK, run = 0;
    for (int d = 255; d >= 0; --d) {
      int c = hist[d];
      if (run + c >= k) { istate[1] = d; istate[0] = k - run; break; }
      run += c;
    }
    istate[2] = 0; istate[4] = 0;
  }
}

__global__ __launch_bounds__(BLK) void compact0_kernel(const u64* __restrict__ in,
    u64* __restrict__ outb, u64* __restrict__ sel, int* __restrict__ istate, int n) {
  int i = blockIdx.x * BLK + threadIdx.x;
  if (i >= n) return;
  u64 kkey = in[i];
  int b = (int)(kkey >> 56);
  int digit = istate[1];
  if (b > digit) {
    sel[atomicAdd(&istate[2], 1)] = kkey;
  } else if (b == digit) {
    outb[atomicAdd(&istate[4], 1)] = kkey;
  }
}

// ---- single block: radix rounds 1..7 + append + bitonic sort + gather ----
__global__ __launch_bounds__(1024) void topk_finish(u64* __restrict__ bufB,
    u64* __restrict__ bufA, u64* __restrict__ sel, const int* __restrict__ istate,
    const float* __restrict__ scores, const float* __restrict__ x,
    float* __restrict__ out) {
  __shared__ int hl[256];
  __shared__ int sh_digit, sh_k, sh_sel, sh_out, sh_cnt;
  __shared__ u64 sk[512];
  int t = threadIdx.x;
  if (t == 0) { sh_cnt = istate[4]; sh_k = istate[0]; sh_sel = istate[2]; }
  __syncthreads();
  u64* cur = bufB;
  u64* nxt = bufA;
  for (int shift = 48; shift >= 0; shift -= 8) {
    for (int i = t; i < 256; i += 1024) hl[i] = 0;
    __syncthreads();
    int cnt = sh_cnt;
    for (int i = t; i < cnt; i += 1024) atomicAdd(&hl[(int)((cur[i] >> shift) & 255ull)], 1);
    __syncthreads();
    if (t == 0) {
      int k = sh_k, run = 0;
      for (int d = 255; d >= 0; --d) {
        int c = hl[d];
        if (run + c >= k) { sh_digit = d; sh_k = k - run; break; }
        run += c;
      }
      sh_out = 0;
    }
    __syncthreads();
    int digit = sh_digit;
    for (int i = t; i < cnt; i += 1024) {
      u64 kk = cur[i];
      int b = (int)((kk >> shift) & 255ull);
      if (b > digit) sel[atomicAdd(&sh_sel, 1)] = kk;
      else if (b == digit) nxt[atomicAdd(&sh_out, 1)] = kk;
    }
    __syncthreads();
    if (t == 0) sh_cnt = sh_out;
    __syncthreads();
    u64* tmp = cur; cur = nxt; nxt = tmp;
  }
  int base = sh_sel, krem = sh_k;
  for (int i = t; i < krem; i += 1024) sel[base + i] = cur[i];
  __syncthreads();
  if (t < 512) sk[t] = sel[t];
  __syncthreads();
  for (int k = 2; k <= 512; k <<= 1) {
    for (int j = k >> 1; j > 0; j >>= 1) {
      if (t < 512) {
        int ixj = t ^ j;
        if (ixj > t) {
          bool dirDesc = ((t & k) == 0);
          u64 A = sk[t], B = sk[ixj];
          bool swp = dirDesc ? (A < B) : (A > B);
          if (swp) { sk[t] = B; sk[ixj] = A; }
        }
      }
      __syncthreads();
    }
  }
  for (int i = t; i < 512 * 16; i += 1024) {
    int r = i >> 4, c = i & 15;
    u64 kk = sk[r];
    int nidx = (int)(~(unsigned int)(kk & 0xffffffffull));
    float v = scores[nidx];
    float4 xv = reinterpret_cast<const float4*>(x)[(size_t)nidx * 16 + c];
    float4 r4; r4.x = xv.x * v; r4.y = xv.y * v; r4.z = xv.z * v; r4.w = xv.w * v;
    reinterpret_cast<float4*>(out)[(size_t)r * 16 + c] = r4;
  }
}

extern "C" void kernel_launch(void* const* d_in, const int* in_sizes, int n_in,
                              void* d_out, int out_size, void* d_ws, size_t ws_size,
                              hipStream_t stream) {
  const int N = in_sizes[0] / 3;
  const int E = in_sizes[1] / 2;

  const float* pos   = (const float*)d_in[0];
  const int*   ei    = (const int*)d_in[1];
  const int*   src   = ei;
  const int*   dst   = ei + E;
  const float* c1_lw = (const float*)d_in[2];
  const float* c1_lb = (const float*)d_in[3];
  const float* c1_w1 = (const float*)d_in[4];
  const float* c1_b1 = (const float*)d_in[5];
  const float* c1_g1 = (const float*)d_in[6];
  const float* c1_be1= (const float*)d_in[7];
  const float* c1_w2 = (const float*)d_in[8];
  const float* c1_b2 = (const float*)d_in[9];
  const float* c2_lw = (const float*)d_in[10];
  const float* c2_lb = (const float*)d_in[11];
  const float* c2_w1 = (const float*)d_in[12];
  const float* c2_b1 = (const float*)d_in[13];
  const float* c2_g1 = (const float*)d_in[14];
  const float* c2_be1= (const float*)d_in[15];
  const float* c2_w2 = (const float*)d_in[16];
  const float* c2_b2 = (const float*)d_in[17];
  const float* poolw = (const float*)d_in[18];

  // ---- workspace layout ----
  float* ws = (float*)d_ws;
  float* x1   = ws;                         // 16N
  float* h1   = ws + (size_t)16 * N;        // 32N
  float* o1   = ws + (size_t)48 * N;        // 16N
  float* res2 = ws;                         // 64N (after x1/h1/o1 dead)
  float* x2   = ws + (size_t)64 * N;        // 64N (res1 uses this region first)
  float* res1 = x2;                         // 16N (dead before lin<16,64> writes x2)
  float* h2   = ws + (size_t)128 * N;       // 128N
  float* o2   = ws + (size_t)256 * N;       // 64N
  float* scores = ws + (size_t)320 * N;     // N
  u64* candA = (u64*)(ws + (size_t)321 * N);            // N
  u64* candB = candA + N;                               // N
  u64* sel   = candB + N;                               // 512
  double* partial = (double*)(sel + TOPK);              // up to 8*nbN*32 doubles (<2MB)
  int* ibase   = (int*)(partial + (size_t)262144);
  int* istate  = ibase;            // 8
  int* hist    = ibase + 8;        // 256
  int* bsum    = ibase + 264;      // 512
  int* deg     = ibase + 776;      // N
  int* rowstart= deg + N;          // N
  int* cursor  = rowstart + N;     // N
  int* eidx    = cursor + N;       // E
  float* fsc   = (float*)(eidx + E);
  float* sc1 = fsc;        float* sh1 = fsc + 32;
  float* sc2 = fsc + 64;   float* sh2 = fsc + 192;     // 320 floats total

  const int nbN = (N + BLK - 1) / BLK;

  // replay-safe zeroing: istate/hist/deg are atomic accumulation targets
  hipMemsetAsync(ibase, 0, (size_t)(776 + N) * sizeof(int), stream);

  // ---- CSR build (shared by both convs) ----
  deg_kernel<<<NPART * PBLK, BLK, 0, stream>>>(dst, deg, E, N);
  blocksum_kernel<<<nbN, BLK, 0, stream>>>(deg, bsum, N);
  scanb_kernel<<<1, 512, 0, stream>>>(bsum, nbN);
  rowstart_kernel<<<nbN, BLK, 0, stream>>>(deg, bsum, rowstart, cursor, N);
  scatter_kernel<<<NPART * PBLK, BLK, 0, stream>>>(src, dst, cursor, eidx, E, N);

  // ---- conv1 ----
  lin_kernel<3, 16, 16><<<dim3(nbN, 1), BLK, 0, stream>>>(pos, c1_lw, c1_lb, x1, nullptr, N);
  agg_kernel<16><<<(N * 16 + BLK - 1) / BLK, BLK, 0, stream>>>(rowstart, deg, eidx, x1, res1, N);
  lin_kernel<16, 32, 32, true><<<dim3(nbN, 1), BLK, 0, stream>>>(res1, c1_w1, c1_b1, h1, partial, N);
  bn_fin3<32, 32><<<32, 256, 0, stream>>>(partial, c1_g1, c1_be1, sc1, sh1, N, nbN);
  mlp2_kernel<32, 16, 16><<<dim3(nbN, 1), BLK, 0, stream>>>(h1, sc1, sh1, c1_w2, c1_b2, o1, N);

  // ---- conv2 ----
  lin_kernel<16, 64, 16><<<dim3(nbN, 4), BLK, 0, stream>>>(o1, c2_lw, c2_lb, x2, nullptr, N);
  agg_kernel<64><<<(N * 64 + BLK - 1) / BLK, BLK, 0, stream>>>(rowstart, deg, eidx, x2, res2, N);
  lin_kernel<64, 128, 16, true><<<dim3(nbN, 8), BLK, 0, stream>>>(res2, c2_w1, c2_b1, h2, partial, N);
  bn_fin3<128, 16><<<128, 256, 0, stream>>>(partial, c2_g1, c2_be1, sc2, sh2, N, nbN);
  mlp2_kernel<128, 64, 16><<<dim3(nbN, 4), BLK, 0, stream>>>(h2, sc2, sh2, c2_w2, c2_b2, o2, N);

  // ---- scores + exact top-K ----
  score_kernel<<<nbN, BLK, 0, stream>>>(o2, poolw, scores, candA, hist, N);
  pick0_kernel<<<1, 64, 0, stream>>>(istate, hist);
  compact0_kernel<<<nbN, BLK, 0, stream>>>(candA, candB, sel, istate, N);
  topk_finish<<<1, 1024, 0, stream>>>(candB, candA, sel, istate, scores, o2, (float*)d_out);

  (void)n_in; (void)out_size; (void)ws_size;
}